// Round 3
// baseline (1043.807 us; speedup 1.0000x reference)
//
#include <hip/hip_runtime.h>
#include <hip/hip_bf16.h>

typedef __attribute__((ext_vector_type(8))) short s16x8;
typedef __attribute__((ext_vector_type(4))) float f32x4;

static __device__ __forceinline__ float b2f(ushort u) {
  union { float f; unsigned bits; } v; v.bits = ((unsigned)u) << 16; return v.f;
}
static __device__ __forceinline__ ushort f2b(float f) {
  __hip_bfloat16 h = __float2bfloat16(f);
  return *reinterpret_cast<ushort*>(&h);
}

// ---------------- dtype detector ----------------
// Examine first 256 ushorts of x. bf16 N(0,1) data: exponent field in
// [113,141] essentially always. f32 data: only the high halves qualify
// (~55% total). flag: 1 = f32, 0 = bf16.
__global__ void detect_dtype(const ushort* __restrict__ xraw, int* __restrict__ flag) {
  __shared__ int cnt;
  if (threadIdx.x == 0) cnt = 0;
  __syncthreads();
  ushort u = xraw[threadIdx.x];
  int e = (u >> 7) & 0xFF;
  if (e >= 113 && e <= 141) atomicAdd(&cnt, 1);
  __syncthreads();
  if (threadIdx.x == 0) *flag = (cnt >= 224) ? 0 : 1;
}

// ---------------- input conversion (dual path) ----------------
__global__ void convert_x(const void* __restrict__ xin, ushort* __restrict__ xb,
                          const int* __restrict__ flag, int n) {
  int i = blockIdx.x * 256 + threadIdx.x;   // handles 4 elements
  int base = i * 4;
  if (base >= n) return;
  if (*flag) {
    const float4 v = ((const float4*)xin)[i];
    xb[base + 0] = f2b(v.x); xb[base + 1] = f2b(v.y);
    xb[base + 2] = f2b(v.z); xb[base + 3] = f2b(v.w);
  } else {
    ((ushort4*)xb)[i] = ((const ushort4*)xin)[i];
  }
}

__global__ void convert_vec(const void* __restrict__ in, ushort* __restrict__ out,
                            const int* __restrict__ flag, int n) {
  int i = blockIdx.x * 256 + threadIdx.x;
  if (i >= n) return;
  out[i] = (*flag) ? f2b(((const float*)in)[i]) : ((const ushort*)in)[i];
}

// transpose + convert: in [R,C] -> out [C,R] bf16
__global__ void transpose_convert(const void* __restrict__ in, ushort* __restrict__ out,
                                  const int* __restrict__ flag, int R, int C) {
  int i = blockIdx.x * 256 + threadIdx.x;
  if (i >= R * C) return;
  int r = i / C, c = i % C;
  ushort v = (*flag) ? f2b(((const float*)in)[i]) : ((const ushort*)in)[i];
  out[c * R + r] = v;
}

// ---------------- CSR build ----------------
__global__ void hist_kernel(const int* __restrict__ dst, int* __restrict__ deg, int E, int N) {
  int e = blockIdx.x * 256 + threadIdx.x;
  if (e < E) {
    unsigned d = (unsigned)dst[e];
    if (d < (unsigned)N) atomicAdd(&deg[d], 1);
  }
}

__global__ __launch_bounds__(1024)
void scan_kernel(const int* __restrict__ deg, int* __restrict__ rowptr,
                 int* __restrict__ pos, int N) {
  __shared__ int sums[1024];
  int t = threadIdx.x;
  int chunk = (N + 1023) >> 10;
  int start = t * chunk;
  int end = min(start + chunk, N);
  int s = 0;
  for (int i = start; i < end; ++i) s += deg[i];
  sums[t] = s;
  __syncthreads();
  for (int off = 1; off < 1024; off <<= 1) {
    int v = (t >= off) ? sums[t - off] : 0;
    __syncthreads();
    sums[t] += v;
    __syncthreads();
  }
  int run = (t == 0) ? 0 : sums[t - 1];
  for (int i = start; i < end; ++i) {
    rowptr[i] = run; pos[i] = run; run += deg[i];
  }
  if (t == 1023) rowptr[N] = run;
}

__global__ void scatter_kernel(const int* __restrict__ src, const int* __restrict__ dstl,
                               int* __restrict__ pos, int* __restrict__ eidx, int E, int N) {
  int e = blockIdx.x * 256 + threadIdx.x;
  if (e < E) {
    unsigned d = (unsigned)dstl[e];
    if (d >= (unsigned)N) return;
    unsigned p = (unsigned)atomicAdd(&pos[d], 1);
    if (p < (unsigned)E) eidx[p] = src[e];
  }
}

// ---------------- mean aggregation (pull, CSR) ----------------
__global__ __launch_bounds__(256)
void agg_mean_kernel(const ushort* __restrict__ xp, const int* __restrict__ rowptr,
                     const int* __restrict__ eidx, ushort* __restrict__ mean,
                     int E, int N) {
  int node = blockIdx.x;
  int f = threadIdx.x;
  int s = rowptr[node], e = rowptr[node + 1];
  if (s < 0) s = 0;
  if (e > E) e = E;
  float acc = 0.f;
  int nv = 0;
  for (int i = s; i < e; ++i) {
    unsigned sn = (unsigned)eidx[i];
    if (sn < (unsigned)N) {
      acc += b2f(xp[(size_t)sn * 256 + f]);
      ++nv;
    }
  }
  if (nv < 1) nv = 1;
  mean[(size_t)node * 256 + f] = f2b(acc / (float)nv);
}

// ---------------- MFMA GEMM: C = act(A1@B1^T + A2@B2^T + bias) ----------------
#define GLD16(g, l) \
  __builtin_amdgcn_global_load_lds((const __attribute__((address_space(1))) void*)(g), \
                                   (__attribute__((address_space(3))) void*)(l), 16, 0, 0)

__global__ __launch_bounds__(256, 2)
void gemm_bf16(const ushort* __restrict__ A1, const ushort* __restrict__ B1,
               const ushort* __restrict__ A2, const ushort* __restrict__ B2,
               const ushort* __restrict__ bias, ushort* __restrict__ C,
               int M, int N, int K1, int K2, int do_relu) {
  __shared__ __align__(16) ushort lsA[128 * 32];
  __shared__ __align__(16) ushort lsB[128 * 32];
  const int tid = threadIdx.x;
  const int lane = tid & 63;
  const int wid = tid >> 6;
  const int wr = wid >> 1, wc = wid & 1;
  const int m0 = blockIdx.x * 128;
  const int n0 = blockIdx.y * 128;
  const int l15 = lane & 15;
  const int lg = lane >> 4;

  f32x4 acc[4][4];
#pragma unroll
  for (int i = 0; i < 4; ++i)
#pragma unroll
    for (int j = 0; j < 4; ++j) {
      acc[i][j][0] = 0.f; acc[i][j][1] = 0.f; acc[i][j][2] = 0.f; acc[i][j][3] = 0.f;
    }

#pragma unroll
  for (int pass = 0; pass < 2; ++pass) {
    const ushort* A = pass ? A2 : A1;
    const ushort* B = pass ? B2 : B1;
    const int K = pass ? K2 : K1;
    if (K == 0) continue;
    for (int k0 = 0; k0 < K; k0 += 32) {
#pragma unroll
      for (int it = 0; it < 2; ++it) {
        int o = tid * 16 + it * 4096;   // byte offset within 8KB tile
        int row = o >> 6;               // 64 bytes per row
        int colb = o & 63;
        const ushort* ga = A + (size_t)(m0 + row) * K + k0 + (colb >> 1);
        GLD16(ga, (char*)lsA + o);
        const ushort* gb = B + (size_t)(n0 + row) * K + k0 + (colb >> 1);
        GLD16(gb, (char*)lsB + o);
      }
      __syncthreads();
      s16x8 af[4], bfr[4];
#pragma unroll
      for (int i = 0; i < 4; ++i)
        af[i] = *(const s16x8*)&lsA[(wr * 64 + i * 16 + l15) * 32 + lg * 8];
#pragma unroll
      for (int j = 0; j < 4; ++j)
        bfr[j] = *(const s16x8*)&lsB[(wc * 64 + j * 16 + l15) * 32 + lg * 8];
#pragma unroll
      for (int i = 0; i < 4; ++i)
#pragma unroll
        for (int j = 0; j < 4; ++j)
          acc[i][j] = __builtin_amdgcn_mfma_f32_16x16x32_bf16(af[i], bfr[j], acc[i][j], 0, 0, 0);
      __syncthreads();
    }
  }

#pragma unroll
  for (int j = 0; j < 4; ++j) {
    int col = n0 + wc * 64 + j * 16 + l15;
    float bv = bias ? b2f(bias[col]) : 0.f;
#pragma unroll
    for (int i = 0; i < 4; ++i) {
      int rbase = m0 + wr * 64 + i * 16 + lg * 4;
#pragma unroll
      for (int r = 0; r < 4; ++r) {
        float v = acc[i][j][r] + bv;
        if (do_relu) v = fmaxf(v, 0.f);
        C[(size_t)(rbase + r) * N + col] = f2b(v);
      }
    }
  }
}

// ---------------- output writers (dual path) ----------------
__global__ void write_h(const ushort* __restrict__ hb, void* __restrict__ dout,
                        const int* __restrict__ flag, long off, int n) {
  int i = blockIdx.x * 256 + threadIdx.x;
  if (i >= n) return;
  ushort u = hb[i];
  if (*flag) ((float*)dout)[off + i] = b2f(u);
  else       ((ushort*)dout)[off + i] = u;
}

__global__ void gather_out(const ushort* __restrict__ hb, const int* __restrict__ map_id,
                           void* __restrict__ dout, const int* __restrict__ flag,
                           int K, int num_nodes, int total, int N) {
  int i = blockIdx.x * 256 + threadIdx.x;
  if (i >= total) return;
  int f = i & 127;
  int row = i >> 7;
  int b = row / K;
  unsigned node = (unsigned)(b * num_nodes + map_id[row]);
  ushort u = (node < (unsigned)N) ? hb[(size_t)node * 128 + f] : (ushort)0;
  if (*flag) ((float*)dout)[i] = b2f(u);
  else       ((ushort*)dout)[i] = u;
}

extern "C" void kernel_launch(void* const* d_in, const int* in_sizes, int n_in,
                              void* d_out, int out_size, void* d_ws, size_t ws_size,
                              hipStream_t stream) {
  const void* x    = d_in[0];
  const int*  ei   = (const int*)d_in[1];
  const int*  mapi = (const int*)d_in[2];
  const void* Wp1  = d_in[4];
  const void* bp1  = d_in[5];
  const void* Wl1  = d_in[6];
  const void* bl1  = d_in[7];
  const void* Wr1  = d_in[8];
  const void* Wp2  = d_in[9];
  const void* bp2  = d_in[10];
  const void* Wl2  = d_in[11];
  const void* bl2  = d_in[12];
  const void* Wr2  = d_in[13];
  const void* Wlin = d_in[14];
  const void* blin = d_in[15];

  const int NN = in_sizes[0] / 256;   // 80000
  const int E  = in_sizes[1] / 2;     // 1.28M
  const int MAPROWS = in_sizes[2];    // 40000
  const int BS = 16;
  const int NUM_NODES = NN / BS;      // 5000
  const int KMAP = MAPROWS / BS;      // 2500
  const int* src = ei;
  const int* dst = ei + E;

  // ---- small scratch in d_out's local_feat region (>=10.24MB in both dtype
  // worlds; we use <7MB; fully dead until the final gather overwrites it) ----
  char* sc = (char*)d_out;
  auto carve_sc = [&](size_t bytes) {
    char* p = sc; sc += (bytes + 255) & ~(size_t)255; return p;
  };
  ushort* Wp1T  = (ushort*)carve_sc(256 * 256 * 2);
  ushort* Wl1T  = (ushort*)carve_sc(256 * 256 * 2);
  ushort* Wr1T  = (ushort*)carve_sc(256 * 256 * 2);
  ushort* Wp2T  = (ushort*)carve_sc(256 * 256 * 2);
  ushort* Wl2T  = (ushort*)carve_sc(128 * 256 * 2);
  ushort* Wr2T  = (ushort*)carve_sc(128 * 256 * 2);
  ushort* WlinT = (ushort*)carve_sc(128 * 128 * 2);
  ushort* bp1c  = (ushort*)carve_sc(256 * 2);
  ushort* bl1c  = (ushort*)carve_sc(256 * 2);
  ushort* bp2c  = (ushort*)carve_sc(256 * 2);
  ushort* bl2c  = (ushort*)carve_sc(128 * 2);
  ushort* blinc = (ushort*)carve_sc(128 * 2);
  int* deg    = (int*)carve_sc((size_t)NN * 4);
  int* rowptr = (int*)carve_sc(((size_t)NN + 1) * 4);
  int* pos    = (int*)carve_sc((size_t)NN * 4);
  int* eidx   = (int*)carve_sc((size_t)E * 4);

  // ---- big buffers in d_ws: flag + 3 x 40.96MB ----
  char* w = (char*)d_ws;
  auto carve = [&](size_t bytes) {
    char* p = w; w += (bytes + 255) & ~(size_t)255; return p;
  };
  int*    flag = (int*)carve(256);
  ushort* xb   = (ushort*)carve((size_t)NN * 256 * 2);  // x_bf16 -> mean2
  ushort* bA   = (ushort*)carve((size_t)NN * 256 * 2);  // xp1 -> h1 -> hfinal
  ushort* bB   = (ushort*)carve((size_t)NN * 256 * 2);  // mean1 -> xp2 -> h2

  // --- dtype detect + conversions ---
  detect_dtype<<<dim3(1), 256, 0, stream>>>((const ushort*)x, flag);
  convert_x<<<dim3((NN * 256 / 4 + 255) / 256), 256, 0, stream>>>(x, xb, flag, NN * 256);
  transpose_convert<<<dim3(256), 256, 0, stream>>>(Wp1, Wp1T, flag, 256, 256);
  transpose_convert<<<dim3(256), 256, 0, stream>>>(Wl1, Wl1T, flag, 256, 256);
  transpose_convert<<<dim3(256), 256, 0, stream>>>(Wr1, Wr1T, flag, 256, 256);
  transpose_convert<<<dim3(256), 256, 0, stream>>>(Wp2, Wp2T, flag, 256, 256);
  transpose_convert<<<dim3(128), 256, 0, stream>>>(Wl2, Wl2T, flag, 256, 128);
  transpose_convert<<<dim3(128), 256, 0, stream>>>(Wr2, Wr2T, flag, 256, 128);
  transpose_convert<<<dim3(64),  256, 0, stream>>>(Wlin, WlinT, flag, 128, 128);
  convert_vec<<<dim3(1), 256, 0, stream>>>(bp1, bp1c, flag, 256);
  convert_vec<<<dim3(1), 256, 0, stream>>>(bl1, bl1c, flag, 256);
  convert_vec<<<dim3(1), 256, 0, stream>>>(bp2, bp2c, flag, 256);
  convert_vec<<<dim3(1), 256, 0, stream>>>(bl2, bl2c, flag, 128);
  convert_vec<<<dim3(1), 256, 0, stream>>>(blin, blinc, flag, 128);

  // --- CSR build ---
  hipMemsetAsync(deg, 0, (size_t)NN * 4, stream);
  hist_kernel<<<dim3((E + 255) / 256), 256, 0, stream>>>(dst, deg, E, NN);
  scan_kernel<<<dim3(1), 1024, 0, stream>>>(deg, rowptr, pos, NN);
  scatter_kernel<<<dim3((E + 255) / 256), 256, 0, stream>>>(src, dst, pos, eidx, E, NN);

  dim3 blk(256);
  dim3 g256(NN / 128, 2);   // N=256
  dim3 g128(NN / 128, 1);   // N=128

  // --- layer 1 ---
  gemm_bf16<<<g256, blk, 0, stream>>>(xb, Wp1T, nullptr, nullptr, bp1c, bA,
                                      NN, 256, 256, 0, 1);                       // xp1
  agg_mean_kernel<<<dim3(NN), blk, 0, stream>>>(bA, rowptr, eidx, bB, E, NN);    // mean1
  gemm_bf16<<<g256, blk, 0, stream>>>(bB, Wl1T, xb, Wr1T, bl1c, bA,
                                      NN, 256, 256, 256, 1);                     // h1

  // --- layer 2 ---
  gemm_bf16<<<g256, blk, 0, stream>>>(bA, Wp2T, nullptr, nullptr, bp2c, bB,
                                      NN, 256, 256, 0, 1);                       // xp2
  agg_mean_kernel<<<dim3(NN), blk, 0, stream>>>(bB, rowptr, eidx, xb, E, NN);    // mean2
  gemm_bf16<<<g128, blk, 0, stream>>>(xb, Wl2T, bA, Wr2T, bl2c, bB,
                                      NN, 128, 256, 256, 1);                     // h2

  // --- final linear (bf16 staging in bA) ---
  gemm_bf16<<<g128, blk, 0, stream>>>(bB, WlinT, nullptr, nullptr, blinc, bA,
                                      NN, 128, 128, 0, 0);                       // h

  // --- outputs ---
  int hN = NN * 128;
  write_h<<<dim3((hN + 255) / 256), 256, 0, stream>>>(bA, d_out, flag,
                                                      (long)MAPROWS * 128, hN);
  int total = MAPROWS * 128;
  gather_out<<<dim3((total + 255) / 256), 256, 0, stream>>>(bA, mapi, d_out, flag,
                                                            KMAP, NUM_NODES, total, NN);
}

// Round 4
// 720.035 us; speedup vs baseline: 1.4497x; 1.4497x over previous
//
#include <hip/hip_runtime.h>
#include <hip/hip_bf16.h>

typedef __attribute__((ext_vector_type(8))) short s16x8;
typedef __attribute__((ext_vector_type(4))) float f32x4;

static __device__ __forceinline__ float b2f(ushort u) {
  union { float f; unsigned bits; } v; v.bits = ((unsigned)u) << 16; return v.f;
}
static __device__ __forceinline__ ushort f2b(float f) {
  __hip_bfloat16 h = __float2bfloat16(f);
  return *reinterpret_cast<ushort*>(&h);
}

// ---------------- dtype detector ----------------
// flag: 1 = inputs are f32, 0 = inputs are bf16.
__global__ void detect_dtype(const ushort* __restrict__ xraw, int* __restrict__ flag) {
  __shared__ int cnt;
  if (threadIdx.x == 0) cnt = 0;
  __syncthreads();
  ushort u = xraw[threadIdx.x];
  int e = (u >> 7) & 0xFF;
  if (e >= 113 && e <= 141) atomicAdd(&cnt, 1);
  __syncthreads();
  if (threadIdx.x == 0) *flag = (cnt >= 224) ? 0 : 1;
}

// ---------------- input conversion (dual path) ----------------
__global__ void convert_x(const void* __restrict__ xin, ushort* __restrict__ xb,
                          const int* __restrict__ flag, int n) {
  int i = blockIdx.x * 256 + threadIdx.x;   // handles 4 elements
  int base = i * 4;
  if (base >= n) return;
  if (*flag) {
    const float4 v = ((const float4*)xin)[i];
    xb[base + 0] = f2b(v.x); xb[base + 1] = f2b(v.y);
    xb[base + 2] = f2b(v.z); xb[base + 3] = f2b(v.w);
  } else {
    ((ushort4*)xb)[i] = ((const ushort4*)xin)[i];
  }
}

__global__ void convert_vec(const void* __restrict__ in, ushort* __restrict__ out,
                            const int* __restrict__ flag, int n) {
  int i = blockIdx.x * 256 + threadIdx.x;
  if (i >= n) return;
  out[i] = (*flag) ? f2b(((const float*)in)[i]) : ((const ushort*)in)[i];
}

// transpose + convert: in [R,C] -> out [C,R] bf16
__global__ void transpose_convert(const void* __restrict__ in, ushort* __restrict__ out,
                                  const int* __restrict__ flag, int R, int C) {
  int i = blockIdx.x * 256 + threadIdx.x;
  if (i >= R * C) return;
  int r = i / C, c = i % C;
  ushort v = (*flag) ? f2b(((const float*)in)[i]) : ((const ushort*)in)[i];
  out[c * R + r] = v;
}

// ---------------- CSR build ----------------
__global__ void hist_kernel(const int* __restrict__ dst, int* __restrict__ deg, int E, int N) {
  int e = blockIdx.x * 256 + threadIdx.x;
  if (e < E) {
    unsigned d = (unsigned)dst[e];
    if (d < (unsigned)N) atomicAdd(&deg[d], 1);
  }
}

__global__ __launch_bounds__(1024)
void scan_kernel(const int* __restrict__ deg, int* __restrict__ rowptr,
                 int* __restrict__ pos, int N) {
  __shared__ int sums[1024];
  int t = threadIdx.x;
  int chunk = (N + 1023) >> 10;
  int start = t * chunk;
  int end = min(start + chunk, N);
  int s = 0;
  for (int i = start; i < end; ++i) s += deg[i];
  sums[t] = s;
  __syncthreads();
  for (int off = 1; off < 1024; off <<= 1) {
    int v = (t >= off) ? sums[t - off] : 0;
    __syncthreads();
    sums[t] += v;
    __syncthreads();
  }
  int run = (t == 0) ? 0 : sums[t - 1];
  for (int i = start; i < end; ++i) {
    rowptr[i] = run; pos[i] = run; run += deg[i];
  }
  if (t == 1023) rowptr[N] = run;
}

__global__ void scatter_kernel(const int* __restrict__ src, const int* __restrict__ dstl,
                               int* __restrict__ pos, int* __restrict__ eidx, int E, int N) {
  int e = blockIdx.x * 256 + threadIdx.x;
  if (e < E) {
    unsigned d = (unsigned)dstl[e];
    if (d >= (unsigned)N) return;
    unsigned p = (unsigned)atomicAdd(&pos[d], 1);
    if (p < (unsigned)E) eidx[p] = src[e];
  }
}

// ---------------- mean aggregation v2 (pull, CSR, wave-per-node) ----------------
// one 64-lane wave per node; lane holds 4 features (ushort4 = 8B load => one
// full 512B row per wave per load instruction). 4 nodes per 256-thread block.
__global__ __launch_bounds__(256)
void agg_mean_v2(const ushort* __restrict__ xp, const int* __restrict__ rowptr,
                 const int* __restrict__ eidx, ushort* __restrict__ mean, int NN) {
  int node = blockIdx.x * 4 + (threadIdx.x >> 6);
  if (node >= NN) return;
  int lane = threadIdx.x & 63;
  int s = rowptr[node], e = rowptr[node + 1];
  float a0 = 0.f, a1 = 0.f, a2 = 0.f, a3 = 0.f;
  for (int base = s; base < e; base += 64) {
    int cnt = min(64, e - base);
    int my = (lane < cnt) ? eidx[base + lane] : 0;
    for (int j = 0; j < cnt; ++j) {
      int sn = __shfl(my, j);
      ushort4 v = *(const ushort4*)&xp[(size_t)sn * 256 + lane * 4];
      a0 += b2f(v.x); a1 += b2f(v.y); a2 += b2f(v.z); a3 += b2f(v.w);
    }
  }
  int c = e - s; if (c < 1) c = 1;
  float inv = 1.f / (float)c;
  ushort4 o;
  o.x = f2b(a0 * inv); o.y = f2b(a1 * inv); o.z = f2b(a2 * inv); o.w = f2b(a3 * inv);
  *(ushort4*)&mean[(size_t)node * 256 + lane * 4] = o;
}

// ---------------- MFMA GEMM: C = act(A1@B1^T + A2@B2^T + bias) ----------------
// If Cf != nullptr: dual-dtype output (flag-selected float32/bf16) for d_out.
#define GLD16(g, l) \
  __builtin_amdgcn_global_load_lds((const __attribute__((address_space(1))) void*)(g), \
                                   (__attribute__((address_space(3))) void*)(l), 16, 0, 0)

__global__ __launch_bounds__(256, 2)
void gemm_bf16(const ushort* __restrict__ A1, const ushort* __restrict__ B1,
               const ushort* __restrict__ A2, const ushort* __restrict__ B2,
               const ushort* __restrict__ bias, ushort* __restrict__ C,
               float* __restrict__ Cf, const int* __restrict__ flag,
               int M, int N, int K1, int K2, int do_relu) {
  __shared__ __align__(16) ushort lsA[128 * 32];
  __shared__ __align__(16) ushort lsB[128 * 32];
  const int tid = threadIdx.x;
  const int lane = tid & 63;
  const int wid = tid >> 6;
  const int wr = wid >> 1, wc = wid & 1;
  const int m0 = blockIdx.x * 128;
  const int n0 = blockIdx.y * 128;
  const int l15 = lane & 15;
  const int lg = lane >> 4;
  const int fl = Cf ? *flag : 0;

  f32x4 acc[4][4];
#pragma unroll
  for (int i = 0; i < 4; ++i)
#pragma unroll
    for (int j = 0; j < 4; ++j) {
      acc[i][j][0] = 0.f; acc[i][j][1] = 0.f; acc[i][j][2] = 0.f; acc[i][j][3] = 0.f;
    }

#pragma unroll
  for (int pass = 0; pass < 2; ++pass) {
    const ushort* A = pass ? A2 : A1;
    const ushort* B = pass ? B2 : B1;
    const int K = pass ? K2 : K1;
    if (K == 0) continue;
    for (int k0 = 0; k0 < K; k0 += 32) {
#pragma unroll
      for (int it = 0; it < 2; ++it) {
        int o = tid * 16 + it * 4096;   // byte offset within 8KB tile
        int row = o >> 6;               // 64 bytes per row
        int colb = o & 63;
        const ushort* ga = A + (size_t)(m0 + row) * K + k0 + (colb >> 1);
        GLD16(ga, (char*)lsA + o);
        const ushort* gb = B + (size_t)(n0 + row) * K + k0 + (colb >> 1);
        GLD16(gb, (char*)lsB + o);
      }
      __syncthreads();
      s16x8 af[4], bfr[4];
#pragma unroll
      for (int i = 0; i < 4; ++i)
        af[i] = *(const s16x8*)&lsA[(wr * 64 + i * 16 + l15) * 32 + lg * 8];
#pragma unroll
      for (int j = 0; j < 4; ++j)
        bfr[j] = *(const s16x8*)&lsB[(wc * 64 + j * 16 + l15) * 32 + lg * 8];
#pragma unroll
      for (int i = 0; i < 4; ++i)
#pragma unroll
        for (int j = 0; j < 4; ++j)
          acc[i][j] = __builtin_amdgcn_mfma_f32_16x16x32_bf16(af[i], bfr[j], acc[i][j], 0, 0, 0);
      __syncthreads();
    }
  }

#pragma unroll
  for (int j = 0; j < 4; ++j) {
    int col = n0 + wc * 64 + j * 16 + l15;
    float bv = bias ? b2f(bias[col]) : 0.f;
#pragma unroll
    for (int i = 0; i < 4; ++i) {
      int rbase = m0 + wr * 64 + i * 16 + lg * 4;
#pragma unroll
      for (int r = 0; r < 4; ++r) {
        float v = acc[i][j][r] + bv;
        if (do_relu) v = fmaxf(v, 0.f);
        size_t idx = (size_t)(rbase + r) * N + col;
        if (Cf) {
          if (fl) Cf[idx] = v;
          else    C[idx] = f2b(v);
        } else {
          C[idx] = f2b(v);
        }
      }
    }
  }
}

// ---------------- kriging gather (reads dual-dtype h region of d_out) ----------------
__global__ void gather_out(const ushort* __restrict__ hb, const float* __restrict__ hf,
                           const int* __restrict__ map_id, void* __restrict__ dout,
                           const int* __restrict__ flag,
                           int K, int num_nodes, int total, int N) {
  int i = blockIdx.x * 256 + threadIdx.x;
  if (i >= total) return;
  int f = i & 127;
  int row = i >> 7;
  int b = row / K;
  unsigned node = (unsigned)(b * num_nodes + map_id[row]);
  bool ok = node < (unsigned)N;
  if (*flag) {
    ((float*)dout)[i] = ok ? hf[(size_t)node * 128 + f] : 0.f;
  } else {
    ((ushort*)dout)[i] = ok ? hb[(size_t)node * 128 + f] : (ushort)0;
  }
}

extern "C" void kernel_launch(void* const* d_in, const int* in_sizes, int n_in,
                              void* d_out, int out_size, void* d_ws, size_t ws_size,
                              hipStream_t stream) {
  const void* x    = d_in[0];
  const int*  ei   = (const int*)d_in[1];
  const int*  mapi = (const int*)d_in[2];
  const void* Wp1  = d_in[4];
  const void* bp1  = d_in[5];
  const void* Wl1  = d_in[6];
  const void* bl1  = d_in[7];
  const void* Wr1  = d_in[8];
  const void* Wp2  = d_in[9];
  const void* bp2  = d_in[10];
  const void* Wl2  = d_in[11];
  const void* bl2  = d_in[12];
  const void* Wr2  = d_in[13];
  const void* Wlin = d_in[14];
  const void* blin = d_in[15];

  const int NN = in_sizes[0] / 256;   // 80000
  const int E  = in_sizes[1] / 2;     // 1.28M
  const int MAPROWS = in_sizes[2];    // 40000
  const int BS = 16;
  const int NUM_NODES = NN / BS;      // 5000
  const int KMAP = MAPROWS / BS;      // 2500
  const int* src = ei;
  const int* dst = ei + E;

  // h output region inside d_out (element offset MAPROWS*128, dtype-dependent base)
  ushort* houtB = (ushort*)d_out + (size_t)MAPROWS * 128;
  float*  houtF = (float*)d_out + (size_t)MAPROWS * 128;

  // ---- small scratch in d_out's local_feat region (dead until final gather) ----
  char* sc = (char*)d_out;
  auto carve_sc = [&](size_t bytes) {
    char* p = sc; sc += (bytes + 255) & ~(size_t)255; return p;
  };
  ushort* Wp1T  = (ushort*)carve_sc(256 * 256 * 2);
  ushort* Wl1T  = (ushort*)carve_sc(256 * 256 * 2);
  ushort* Wr1T  = (ushort*)carve_sc(256 * 256 * 2);
  ushort* Wp2T  = (ushort*)carve_sc(256 * 256 * 2);
  ushort* Wl2T  = (ushort*)carve_sc(128 * 256 * 2);
  ushort* Wr2T  = (ushort*)carve_sc(128 * 256 * 2);
  ushort* WlinT = (ushort*)carve_sc(128 * 128 * 2);
  ushort* bp1c  = (ushort*)carve_sc(256 * 2);
  ushort* bl1c  = (ushort*)carve_sc(256 * 2);
  ushort* bp2c  = (ushort*)carve_sc(256 * 2);
  ushort* bl2c  = (ushort*)carve_sc(128 * 2);
  ushort* blinc = (ushort*)carve_sc(128 * 2);
  int* deg    = (int*)carve_sc((size_t)NN * 4);
  int* rowptr = (int*)carve_sc(((size_t)NN + 1) * 4);
  int* pos    = (int*)carve_sc((size_t)NN * 4);
  int* eidx   = (int*)carve_sc((size_t)E * 4);

  // ---- big buffers in d_ws: flag + 3 x 40.96MB ----
  char* w = (char*)d_ws;
  auto carve = [&](size_t bytes) {
    char* p = w; w += (bytes + 255) & ~(size_t)255; return p;
  };
  int*    flag = (int*)carve(256);
  ushort* xb   = (ushort*)carve((size_t)NN * 256 * 2);  // x_bf16 -> mean2
  ushort* bA   = (ushort*)carve((size_t)NN * 256 * 2);  // xp1 -> h1
  ushort* bB   = (ushort*)carve((size_t)NN * 256 * 2);  // mean1 -> xp2 -> h2

  // --- dtype detect + conversions ---
  detect_dtype<<<dim3(1), 256, 0, stream>>>((const ushort*)x, flag);
  convert_x<<<dim3((NN * 256 / 4 + 255) / 256), 256, 0, stream>>>(x, xb, flag, NN * 256);
  transpose_convert<<<dim3(256), 256, 0, stream>>>(Wp1, Wp1T, flag, 256, 256);
  transpose_convert<<<dim3(256), 256, 0, stream>>>(Wl1, Wl1T, flag, 256, 256);
  transpose_convert<<<dim3(256), 256, 0, stream>>>(Wr1, Wr1T, flag, 256, 256);
  transpose_convert<<<dim3(256), 256, 0, stream>>>(Wp2, Wp2T, flag, 256, 256);
  transpose_convert<<<dim3(128), 256, 0, stream>>>(Wl2, Wl2T, flag, 256, 128);
  transpose_convert<<<dim3(128), 256, 0, stream>>>(Wr2, Wr2T, flag, 256, 128);
  transpose_convert<<<dim3(64),  256, 0, stream>>>(Wlin, WlinT, flag, 128, 128);
  convert_vec<<<dim3(1), 256, 0, stream>>>(bp1, bp1c, flag, 256);
  convert_vec<<<dim3(1), 256, 0, stream>>>(bl1, bl1c, flag, 256);
  convert_vec<<<dim3(1), 256, 0, stream>>>(bp2, bp2c, flag, 256);
  convert_vec<<<dim3(1), 256, 0, stream>>>(bl2, bl2c, flag, 128);
  convert_vec<<<dim3(1), 256, 0, stream>>>(blin, blinc, flag, 128);

  // --- CSR build ---
  hipMemsetAsync(deg, 0, (size_t)NN * 4, stream);
  hist_kernel<<<dim3((E + 255) / 256), 256, 0, stream>>>(dst, deg, E, NN);
  scan_kernel<<<dim3(1), 1024, 0, stream>>>(deg, rowptr, pos, NN);
  scatter_kernel<<<dim3((E + 255) / 256), 256, 0, stream>>>(src, dst, pos, eidx, E, NN);

  dim3 blk(256);
  dim3 g256(NN / 128, 2);   // N=256
  dim3 g128(NN / 128, 1);   // N=128
  dim3 gagg((NN + 3) / 4);

  // --- layer 1 ---
  gemm_bf16<<<g256, blk, 0, stream>>>(xb, Wp1T, nullptr, nullptr, bp1c, bA,
                                      nullptr, nullptr, NN, 256, 256, 0, 1);        // xp1
  agg_mean_v2<<<gagg, blk, 0, stream>>>(bA, rowptr, eidx, bB, NN);                  // mean1
  gemm_bf16<<<g256, blk, 0, stream>>>(bB, Wl1T, xb, Wr1T, bl1c, bA,
                                      nullptr, nullptr, NN, 256, 256, 256, 1);      // h1

  // --- layer 2 ---
  gemm_bf16<<<g256, blk, 0, stream>>>(bA, Wp2T, nullptr, nullptr, bp2c, bB,
                                      nullptr, nullptr, NN, 256, 256, 0, 1);        // xp2
  agg_mean_v2<<<gagg, blk, 0, stream>>>(bB, rowptr, eidx, xb, NN);                  // mean2
  gemm_bf16<<<g128, blk, 0, stream>>>(xb, Wl2T, bA, Wr2T, bl2c, bB,
                                      nullptr, nullptr, NN, 128, 256, 256, 1);      // h2

  // --- final linear: write dual-dtype h straight into d_out h region ---
  gemm_bf16<<<g128, blk, 0, stream>>>(bB, WlinT, nullptr, nullptr, blinc, houtB,
                                      houtF, flag, NN, 128, 128, 0, 0);

  // --- kriging gather -> d_out local_feat region (overwrites scratch, last use) ---
  int total = MAPROWS * 128;
  gather_out<<<dim3((total + 255) / 256), 256, 0, stream>>>(houtB, houtF, mapi, d_out,
                                                            flag, KMAP, NUM_NODES, total, NN);
}

// Round 5
// 569.220 us; speedup vs baseline: 1.8337x; 1.2650x over previous
//
#include <hip/hip_runtime.h>
#include <hip/hip_bf16.h>

typedef __attribute__((ext_vector_type(8))) short s16x8;
typedef __attribute__((ext_vector_type(4))) float f32x4;

static __device__ __forceinline__ float b2f(ushort u) {
  union { float f; unsigned bits; } v; v.bits = ((unsigned)u) << 16; return v.f;
}
static __device__ __forceinline__ ushort f2b(float f) {
  __hip_bfloat16 h = __float2bfloat16(f);
  return *reinterpret_cast<ushort*>(&h);
}

// ---------------- dtype detector ----------------
// flag: 1 = inputs are f32, 0 = inputs are bf16.
__global__ void detect_dtype(const ushort* __restrict__ xraw, int* __restrict__ flag) {
  __shared__ int cnt;
  if (threadIdx.x == 0) cnt = 0;
  __syncthreads();
  ushort u = xraw[threadIdx.x];
  int e = (u >> 7) & 0xFF;
  if (e >= 113 && e <= 141) atomicAdd(&cnt, 1);
  __syncthreads();
  if (threadIdx.x == 0) *flag = (cnt >= 224) ? 0 : 1;
}

// ---------------- input conversion (dual path) ----------------
__global__ void convert_x(const void* __restrict__ xin, ushort* __restrict__ xb,
                          const int* __restrict__ flag, int n) {
  int i = blockIdx.x * 256 + threadIdx.x;   // handles 4 elements
  int base = i * 4;
  if (base >= n) return;
  if (*flag) {
    const float4 v = ((const float4*)xin)[i];
    xb[base + 0] = f2b(v.x); xb[base + 1] = f2b(v.y);
    xb[base + 2] = f2b(v.z); xb[base + 3] = f2b(v.w);
  } else {
    ((ushort4*)xb)[i] = ((const ushort4*)xin)[i];
  }
}

__global__ void convert_vec(const void* __restrict__ in, ushort* __restrict__ out,
                            const int* __restrict__ flag, int n) {
  int i = blockIdx.x * 256 + threadIdx.x;
  if (i >= n) return;
  out[i] = (*flag) ? f2b(((const float*)in)[i]) : ((const ushort*)in)[i];
}

// transpose + convert: in [R,C] -> out [C,R] bf16
__global__ void transpose_convert(const void* __restrict__ in, ushort* __restrict__ out,
                                  const int* __restrict__ flag, int R, int C) {
  int i = blockIdx.x * 256 + threadIdx.x;
  if (i >= R * C) return;
  int r = i / C, c = i % C;
  ushort v = (*flag) ? f2b(((const float*)in)[i]) : ((const ushort*)in)[i];
  out[c * R + r] = v;
}

// ---------------- CSR build ----------------
__global__ void hist_kernel(const int* __restrict__ dst, int* __restrict__ deg, int E, int N) {
  int e = blockIdx.x * 256 + threadIdx.x;
  if (e < E) {
    unsigned d = (unsigned)dst[e];
    if (d < (unsigned)N) atomicAdd(&deg[d], 1);
  }
}

// 3-phase device-wide exclusive scan (1024 elements per block, 4/thread)
__global__ __launch_bounds__(256)
void scan_phaseA(const int* __restrict__ deg, int* __restrict__ bsum, int N) {
  int b = blockIdx.x, t = threadIdx.x;
  int i0 = b * 1024 + t * 4;
  int s = 0;
#pragma unroll
  for (int k = 0; k < 4; ++k) {
    int i = i0 + k;
    if (i < N) s += deg[i];
  }
  __shared__ int red[256];
  red[t] = s; __syncthreads();
  for (int off = 128; off > 0; off >>= 1) {
    if (t < off) red[t] += red[t + off];
    __syncthreads();
  }
  if (t == 0) bsum[b] = red[0];
}

__global__ __launch_bounds__(256)
void scan_phaseB(const int* __restrict__ bsum, int* __restrict__ ebsum,
                 int* __restrict__ rowptr, int B, int N) {
  int t = threadIdx.x;
  __shared__ int sh[256];
  int v = (t < B) ? bsum[t] : 0;
  sh[t] = v; __syncthreads();
  for (int off = 1; off < 256; off <<= 1) {
    int u = (t >= off) ? sh[t - off] : 0;
    __syncthreads();
    sh[t] += u;
    __syncthreads();
  }
  if (t < B) ebsum[t] = sh[t] - v;
  if (t == B - 1) rowptr[N] = sh[t];
}

__global__ __launch_bounds__(256)
void scan_phaseC(const int* __restrict__ deg, const int* __restrict__ ebsum,
                 int* __restrict__ rowptr, int* __restrict__ pos, int N) {
  int b = blockIdx.x, t = threadIdx.x;
  int i0 = b * 1024 + t * 4;
  int v[4]; int s = 0;
#pragma unroll
  for (int k = 0; k < 4; ++k) {
    int i = i0 + k;
    v[k] = (i < N) ? deg[i] : 0;
    s += v[k];
  }
  __shared__ int sh[256];
  sh[t] = s; __syncthreads();
  for (int off = 1; off < 256; off <<= 1) {
    int u = (t >= off) ? sh[t - off] : 0;
    __syncthreads();
    sh[t] += u;
    __syncthreads();
  }
  int run = ebsum[b] + sh[t] - s;
#pragma unroll
  for (int k = 0; k < 4; ++k) {
    int i = i0 + k;
    if (i < N) { rowptr[i] = run; pos[i] = run; run += v[k]; }
  }
}

__global__ void scatter_kernel(const int* __restrict__ src, const int* __restrict__ dstl,
                               int* __restrict__ pos, int* __restrict__ eidx, int E, int N) {
  int e = blockIdx.x * 256 + threadIdx.x;
  if (e < E) {
    unsigned d = (unsigned)dstl[e];
    if (d >= (unsigned)N) return;
    unsigned p = (unsigned)atomicAdd(&pos[d], 1);
    if (p < (unsigned)E) eidx[p] = src[e];
  }
}

// ---------------- mean aggregation v2 (pull, CSR, wave-per-node) ----------------
__global__ __launch_bounds__(256)
void agg_mean_v2(const ushort* __restrict__ xp, const int* __restrict__ rowptr,
                 const int* __restrict__ eidx, ushort* __restrict__ mean, int NN) {
  int node = blockIdx.x * 4 + (threadIdx.x >> 6);
  if (node >= NN) return;
  int lane = threadIdx.x & 63;
  int s = rowptr[node], e = rowptr[node + 1];
  float a0 = 0.f, a1 = 0.f, a2 = 0.f, a3 = 0.f;
  for (int base = s; base < e; base += 64) {
    int cnt = min(64, e - base);
    int my = (lane < cnt) ? eidx[base + lane] : 0;
    for (int j = 0; j < cnt; ++j) {
      int sn = __shfl(my, j);
      ushort4 v = *(const ushort4*)&xp[(size_t)sn * 256 + lane * 4];
      a0 += b2f(v.x); a1 += b2f(v.y); a2 += b2f(v.z); a3 += b2f(v.w);
    }
  }
  int c = e - s; if (c < 1) c = 1;
  float inv = 1.f / (float)c;
  ushort4 o;
  o.x = f2b(a0 * inv); o.y = f2b(a1 * inv); o.z = f2b(a2 * inv); o.w = f2b(a3 * inv);
  *(ushort4*)&mean[(size_t)node * 256 + lane * 4] = o;
}

// ---------------- MFMA GEMM: C = act(A1@B1^T + A2@B2^T + bias) ----------------
#define GLD16(g, l) \
  __builtin_amdgcn_global_load_lds((const __attribute__((address_space(1))) void*)(g), \
                                   (__attribute__((address_space(3))) void*)(l), 16, 0, 0)

__global__ __launch_bounds__(256, 2)
void gemm_bf16(const ushort* __restrict__ A1, const ushort* __restrict__ B1,
               const ushort* __restrict__ A2, const ushort* __restrict__ B2,
               const ushort* __restrict__ bias, ushort* __restrict__ C,
               float* __restrict__ Cf, const int* __restrict__ flag,
               int M, int N, int K1, int K2, int do_relu) {
  __shared__ __align__(16) ushort lsA[128 * 32];
  __shared__ __align__(16) ushort lsB[128 * 32];
  const int tid = threadIdx.x;
  const int lane = tid & 63;
  const int wid = tid >> 6;
  const int wr = wid >> 1, wc = wid & 1;
  const int m0 = blockIdx.x * 128;
  const int n0 = blockIdx.y * 128;
  const int l15 = lane & 15;
  const int lg = lane >> 4;
  const int fl = Cf ? *flag : 0;

  f32x4 acc[4][4];
#pragma unroll
  for (int i = 0; i < 4; ++i)
#pragma unroll
    for (int j = 0; j < 4; ++j) {
      acc[i][j][0] = 0.f; acc[i][j][1] = 0.f; acc[i][j][2] = 0.f; acc[i][j][3] = 0.f;
    }

#pragma unroll
  for (int pass = 0; pass < 2; ++pass) {
    const ushort* A = pass ? A2 : A1;
    const ushort* B = pass ? B2 : B1;
    const int K = pass ? K2 : K1;
    if (K == 0) continue;
    for (int k0 = 0; k0 < K; k0 += 32) {
#pragma unroll
      for (int it = 0; it < 2; ++it) {
        int o = tid * 16 + it * 4096;   // byte offset within 8KB tile
        int row = o >> 6;               // 64 bytes per row
        int colb = o & 63;
        const ushort* ga = A + (size_t)(m0 + row) * K + k0 + (colb >> 1);
        GLD16(ga, (char*)lsA + o);
        const ushort* gb = B + (size_t)(n0 + row) * K + k0 + (colb >> 1);
        GLD16(gb, (char*)lsB + o);
      }
      __syncthreads();
      s16x8 af[4], bfr[4];
#pragma unroll
      for (int i = 0; i < 4; ++i)
        af[i] = *(const s16x8*)&lsA[(wr * 64 + i * 16 + l15) * 32 + lg * 8];
#pragma unroll
      for (int j = 0; j < 4; ++j)
        bfr[j] = *(const s16x8*)&lsB[(wc * 64 + j * 16 + l15) * 32 + lg * 8];
#pragma unroll
      for (int i = 0; i < 4; ++i)
#pragma unroll
        for (int j = 0; j < 4; ++j)
          acc[i][j] = __builtin_amdgcn_mfma_f32_16x16x32_bf16(af[i], bfr[j], acc[i][j], 0, 0, 0);
      __syncthreads();
    }
  }

#pragma unroll
  for (int j = 0; j < 4; ++j) {
    int col = n0 + wc * 64 + j * 16 + l15;
    float bv = bias ? b2f(bias[col]) : 0.f;
#pragma unroll
    for (int i = 0; i < 4; ++i) {
      int rbase = m0 + wr * 64 + i * 16 + lg * 4;
#pragma unroll
      for (int r = 0; r < 4; ++r) {
        float v = acc[i][j][r] + bv;
        if (do_relu) v = fmaxf(v, 0.f);
        size_t idx = (size_t)(rbase + r) * N + col;
        if (Cf) {
          if (fl) Cf[idx] = v;
          else    C[idx] = f2b(v);
        } else {
          C[idx] = f2b(v);
        }
      }
    }
  }
}

// ---------------- kriging gather (reads dual-dtype h region of d_out) ----------------
__global__ void gather_out(const ushort* __restrict__ hb, const float* __restrict__ hf,
                           const int* __restrict__ map_id, void* __restrict__ dout,
                           const int* __restrict__ flag,
                           int K, int num_nodes, int total, int N) {
  int i = blockIdx.x * 256 + threadIdx.x;
  if (i >= total) return;
  int f = i & 127;
  int row = i >> 7;
  int b = row / K;
  unsigned node = (unsigned)(b * num_nodes + map_id[row]);
  bool ok = node < (unsigned)N;
  if (*flag) {
    ((float*)dout)[i] = ok ? hf[(size_t)node * 128 + f] : 0.f;
  } else {
    ((ushort*)dout)[i] = ok ? hb[(size_t)node * 128 + f] : (ushort)0;
  }
}

extern "C" void kernel_launch(void* const* d_in, const int* in_sizes, int n_in,
                              void* d_out, int out_size, void* d_ws, size_t ws_size,
                              hipStream_t stream) {
  const void* x    = d_in[0];
  const int*  ei   = (const int*)d_in[1];
  const int*  mapi = (const int*)d_in[2];
  const void* Wp1  = d_in[4];
  const void* bp1  = d_in[5];
  const void* Wl1  = d_in[6];
  const void* bl1  = d_in[7];
  const void* Wr1  = d_in[8];
  const void* Wp2  = d_in[9];
  const void* bp2  = d_in[10];
  const void* Wl2  = d_in[11];
  const void* bl2  = d_in[12];
  const void* Wr2  = d_in[13];
  const void* Wlin = d_in[14];
  const void* blin = d_in[15];

  const int NN = in_sizes[0] / 256;   // 80000
  const int E  = in_sizes[1] / 2;     // 1.28M
  const int MAPROWS = in_sizes[2];    // 40000
  const int BS = 16;
  const int NUM_NODES = NN / BS;      // 5000
  const int KMAP = MAPROWS / BS;      // 2500
  const int* src = ei;
  const int* dst = ei + E;

  // h output region inside d_out (element offset MAPROWS*128, dtype-dependent base)
  ushort* houtB = (ushort*)d_out + (size_t)MAPROWS * 128;
  float*  houtF = (float*)d_out + (size_t)MAPROWS * 128;

  // ---- small scratch in d_out's local_feat region (dead until final gather) ----
  char* sc = (char*)d_out;
  auto carve_sc = [&](size_t bytes) {
    char* p = sc; sc += (bytes + 255) & ~(size_t)255; return p;
  };
  ushort* Wp1T  = (ushort*)carve_sc(256 * 256 * 2);
  ushort* Wl1T  = (ushort*)carve_sc(256 * 256 * 2);
  ushort* Wr1T  = (ushort*)carve_sc(256 * 256 * 2);
  ushort* Wp2T  = (ushort*)carve_sc(256 * 256 * 2);
  ushort* Wl2T  = (ushort*)carve_sc(128 * 256 * 2);
  ushort* Wr2T  = (ushort*)carve_sc(128 * 256 * 2);
  ushort* WlinT = (ushort*)carve_sc(128 * 128 * 2);
  ushort* bp1c  = (ushort*)carve_sc(256 * 2);
  ushort* bl1c  = (ushort*)carve_sc(256 * 2);
  ushort* bp2c  = (ushort*)carve_sc(256 * 2);
  ushort* bl2c  = (ushort*)carve_sc(128 * 2);
  ushort* blinc = (ushort*)carve_sc(128 * 2);
  int* deg    = (int*)carve_sc((size_t)NN * 4);
  int* rowptr = (int*)carve_sc(((size_t)NN + 1) * 4);
  int* pos    = (int*)carve_sc((size_t)NN * 4);
  int* eidx   = (int*)carve_sc((size_t)E * 4);
  int* bsum   = (int*)carve_sc(1024);
  int* ebsum  = (int*)carve_sc(1024);

  // ---- big buffers in d_ws: flag + 3 x 40.96MB ----
  char* w = (char*)d_ws;
  auto carve = [&](size_t bytes) {
    char* p = w; w += (bytes + 255) & ~(size_t)255; return p;
  };
  int*    flag = (int*)carve(256);
  ushort* xb   = (ushort*)carve((size_t)NN * 256 * 2);  // x_bf16 -> mean2
  ushort* bA   = (ushort*)carve((size_t)NN * 256 * 2);  // xp1 -> h1
  ushort* bB   = (ushort*)carve((size_t)NN * 256 * 2);  // mean1 -> xp2 -> h2

  // --- dtype detect + conversions ---
  detect_dtype<<<dim3(1), 256, 0, stream>>>((const ushort*)x, flag);
  convert_x<<<dim3((NN * 256 / 4 + 255) / 256), 256, 0, stream>>>(x, xb, flag, NN * 256);
  transpose_convert<<<dim3(256), 256, 0, stream>>>(Wp1, Wp1T, flag, 256, 256);
  transpose_convert<<<dim3(256), 256, 0, stream>>>(Wl1, Wl1T, flag, 256, 256);
  transpose_convert<<<dim3(256), 256, 0, stream>>>(Wr1, Wr1T, flag, 256, 256);
  transpose_convert<<<dim3(256), 256, 0, stream>>>(Wp2, Wp2T, flag, 256, 256);
  transpose_convert<<<dim3(128), 256, 0, stream>>>(Wl2, Wl2T, flag, 256, 128);
  transpose_convert<<<dim3(128), 256, 0, stream>>>(Wr2, Wr2T, flag, 256, 128);
  transpose_convert<<<dim3(64),  256, 0, stream>>>(Wlin, WlinT, flag, 128, 128);
  convert_vec<<<dim3(1), 256, 0, stream>>>(bp1, bp1c, flag, 256);
  convert_vec<<<dim3(1), 256, 0, stream>>>(bl1, bl1c, flag, 256);
  convert_vec<<<dim3(1), 256, 0, stream>>>(bp2, bp2c, flag, 256);
  convert_vec<<<dim3(1), 256, 0, stream>>>(bl2, bl2c, flag, 128);
  convert_vec<<<dim3(1), 256, 0, stream>>>(blin, blinc, flag, 128);

  // --- CSR build ---
  hipMemsetAsync(deg, 0, (size_t)NN * 4, stream);
  hist_kernel<<<dim3((E + 255) / 256), 256, 0, stream>>>(dst, deg, E, NN);
  int SB = (NN + 1023) / 1024;   // 79 scan blocks (<=256 supported)
  scan_phaseA<<<dim3(SB), 256, 0, stream>>>(deg, bsum, NN);
  scan_phaseB<<<dim3(1), 256, 0, stream>>>(bsum, ebsum, rowptr, SB, NN);
  scan_phaseC<<<dim3(SB), 256, 0, stream>>>(deg, ebsum, rowptr, pos, NN);
  scatter_kernel<<<dim3((E + 255) / 256), 256, 0, stream>>>(src, dst, pos, eidx, E, NN);

  dim3 blk(256);
  dim3 g256(NN / 128, 2);   // N=256
  dim3 g128(NN / 128, 1);   // N=128
  dim3 gagg((NN + 3) / 4);

  // --- layer 1 ---
  gemm_bf16<<<g256, blk, 0, stream>>>(xb, Wp1T, nullptr, nullptr, bp1c, bA,
                                      nullptr, nullptr, NN, 256, 256, 0, 1);        // xp1
  agg_mean_v2<<<gagg, blk, 0, stream>>>(bA, rowptr, eidx, bB, NN);                  // mean1
  gemm_bf16<<<g256, blk, 0, stream>>>(bB, Wl1T, xb, Wr1T, bl1c, bA,
                                      nullptr, nullptr, NN, 256, 256, 256, 1);      // h1

  // --- layer 2 ---
  gemm_bf16<<<g256, blk, 0, stream>>>(bA, Wp2T, nullptr, nullptr, bp2c, bB,
                                      nullptr, nullptr, NN, 256, 256, 0, 1);        // xp2
  agg_mean_v2<<<gagg, blk, 0, stream>>>(bB, rowptr, eidx, xb, NN);                  // mean2
  gemm_bf16<<<g128, blk, 0, stream>>>(xb, Wl2T, bA, Wr2T, bl2c, bB,
                                      nullptr, nullptr, NN, 128, 256, 256, 1);      // h2

  // --- final linear: write dual-dtype h straight into d_out h region ---
  gemm_bf16<<<g128, blk, 0, stream>>>(bB, WlinT, nullptr, nullptr, blinc, houtB,
                                      houtF, flag, NN, 128, 128, 0, 0);

  // --- kriging gather -> d_out local_feat region (overwrites scratch, last use) ---
  int total = MAPROWS * 128;
  gather_out<<<dim3((total + 255) / 256), 256, 0, stream>>>(houtB, houtF, mapi, d_out,
                                                            flag, KMAP, NUM_NODES, total, NN);
}

// Round 6
// 529.166 us; speedup vs baseline: 1.9726x; 1.0757x over previous
//
#include <hip/hip_runtime.h>
#include <hip/hip_bf16.h>

typedef __attribute__((ext_vector_type(8))) short s16x8;
typedef __attribute__((ext_vector_type(8))) ushort u16x8;
typedef __attribute__((ext_vector_type(4))) float f32x4;

static __device__ __forceinline__ float b2f(ushort u) {
  union { float f; unsigned bits; } v; v.bits = ((unsigned)u) << 16; return v.f;
}
static __device__ __forceinline__ ushort f2b(float f) {
  __hip_bfloat16 h = __float2bfloat16(f);
  return *reinterpret_cast<ushort*>(&h);
}

// ---------------- dtype detector ----------------
// flag: 1 = inputs are f32, 0 = inputs are bf16.
__global__ void detect_dtype(const ushort* __restrict__ xraw, int* __restrict__ flag) {
  __shared__ int cnt;
  if (threadIdx.x == 0) cnt = 0;
  __syncthreads();
  ushort u = xraw[threadIdx.x];
  int e = (u >> 7) & 0xFF;
  if (e >= 113 && e <= 141) atomicAdd(&cnt, 1);
  __syncthreads();
  if (threadIdx.x == 0) *flag = (cnt >= 224) ? 0 : 1;
}

// ---------------- input conversion (dual path) ----------------
__global__ void convert_x(const void* __restrict__ xin, ushort* __restrict__ xb,
                          const int* __restrict__ flag, int n) {
  int i = blockIdx.x * 256 + threadIdx.x;   // handles 4 elements
  int base = i * 4;
  if (base >= n) return;
  if (*flag) {
    const float4 v = ((const float4*)xin)[i];
    xb[base + 0] = f2b(v.x); xb[base + 1] = f2b(v.y);
    xb[base + 2] = f2b(v.z); xb[base + 3] = f2b(v.w);
  } else {
    ((ushort4*)xb)[i] = ((const ushort4*)xin)[i];
  }
}

// ---------------- batched weight transpose+convert (7 matrices, 1 launch) ----------------
struct WDesc { const void* src; ushort* dst; int R, C; };
struct WPack { WDesc d[7]; };

__global__ void transpose_convert_all(WPack p, const int* __restrict__ flag) {
  const WDesc& d = p.d[blockIdx.y];
  int i = blockIdx.x * 256 + threadIdx.x;
  if (i >= d.R * d.C) return;
  int r = i / d.C, c = i % d.C;
  ushort v = (*flag) ? f2b(((const float*)d.src)[i]) : ((const ushort*)d.src)[i];
  d.dst[c * d.R + r] = v;
}

// ---------------- batched bias convert (5 vectors, 1 launch) ----------------
struct BPack { WDesc d[5]; };
__global__ void convert_vec_all(BPack p, const int* __restrict__ flag) {
  const WDesc& d = p.d[blockIdx.y];
  int i = threadIdx.x;
  if (i >= d.R) return;
  d.dst[i] = (*flag) ? f2b(((const float*)d.src)[i]) : ((const ushort*)d.src)[i];
}

// ---------------- CSR build ----------------
__global__ void hist_kernel(const int* __restrict__ dst, int* __restrict__ deg, int E, int N) {
  int e = blockIdx.x * 256 + threadIdx.x;
  if (e < E) {
    unsigned d = (unsigned)dst[e];
    if (d < (unsigned)N) atomicAdd(&deg[d], 1);
  }
}

// 3-phase device-wide exclusive scan (1024 elements per block, 4/thread)
__global__ __launch_bounds__(256)
void scan_phaseA(const int* __restrict__ deg, int* __restrict__ bsum, int N) {
  int b = blockIdx.x, t = threadIdx.x;
  int i0 = b * 1024 + t * 4;
  int s = 0;
#pragma unroll
  for (int k = 0; k < 4; ++k) {
    int i = i0 + k;
    if (i < N) s += deg[i];
  }
  __shared__ int red[256];
  red[t] = s; __syncthreads();
  for (int off = 128; off > 0; off >>= 1) {
    if (t < off) red[t] += red[t + off];
    __syncthreads();
  }
  if (t == 0) bsum[b] = red[0];
}

__global__ __launch_bounds__(256)
void scan_phaseB(const int* __restrict__ bsum, int* __restrict__ ebsum,
                 int* __restrict__ rowptr, int B, int N) {
  int t = threadIdx.x;
  __shared__ int sh[256];
  int v = (t < B) ? bsum[t] : 0;
  sh[t] = v; __syncthreads();
  for (int off = 1; off < 256; off <<= 1) {
    int u = (t >= off) ? sh[t - off] : 0;
    __syncthreads();
    sh[t] += u;
    __syncthreads();
  }
  if (t < B) ebsum[t] = sh[t] - v;
  if (t == B - 1) rowptr[N] = sh[t];
}

__global__ __launch_bounds__(256)
void scan_phaseC(const int* __restrict__ deg, const int* __restrict__ ebsum,
                 int* __restrict__ rowptr, int* __restrict__ pos, int N) {
  int b = blockIdx.x, t = threadIdx.x;
  int i0 = b * 1024 + t * 4;
  int v[4]; int s = 0;
#pragma unroll
  for (int k = 0; k < 4; ++k) {
    int i = i0 + k;
    v[k] = (i < N) ? deg[i] : 0;
    s += v[k];
  }
  __shared__ int sh[256];
  sh[t] = s; __syncthreads();
  for (int off = 1; off < 256; off <<= 1) {
    int u = (t >= off) ? sh[t - off] : 0;
    __syncthreads();
    sh[t] += u;
    __syncthreads();
  }
  int run = ebsum[b] + sh[t] - s;
#pragma unroll
  for (int k = 0; k < 4; ++k) {
    int i = i0 + k;
    if (i < N) { rowptr[i] = run; pos[i] = run; run += v[k]; }
  }
}

__global__ void scatter_kernel(const int* __restrict__ src, const int* __restrict__ dstl,
                               int* __restrict__ pos, int* __restrict__ eidx, int E, int N) {
  int e = blockIdx.x * 256 + threadIdx.x;
  if (e < E) {
    unsigned d = (unsigned)dstl[e];
    if (d >= (unsigned)N) return;
    unsigned p = (unsigned)atomicAdd(&pos[d], 1);
    if (p < (unsigned)E) eidx[p] = src[e];
  }
}

// ---------------- mean aggregation v3 (wave-per-node, 16B/lane, 2 rows/load) ----------------
// lanes 0-31 handle even neighbors, lanes 32-63 odd neighbors; each lane loads
// 16B (8 features). One load instruction covers 2 full 512B rows.
__global__ __launch_bounds__(256)
void agg_mean_v3(const ushort* __restrict__ xp, const int* __restrict__ rowptr,
                 const int* __restrict__ eidx, ushort* __restrict__ mean, int NN) {
  int node = blockIdx.x * 4 + (threadIdx.x >> 6);
  if (node >= NN) return;
  int lane = threadIdx.x & 63;
  int half = lane >> 5;        // 0 = even neighbor, 1 = odd neighbor
  int l32 = lane & 31;         // feature block: features l32*8 .. +7
  int s = rowptr[node], e = rowptr[node + 1];
  float a[8];
#pragma unroll
  for (int k = 0; k < 8; ++k) a[k] = 0.f;

  for (int base = s; base < e; base += 64) {
    int cnt = min(64, e - base);
    int my = (lane < cnt) ? eidx[base + lane] : 0;
    int full = cnt >> 1;
#pragma unroll 2
    for (int it = 0; it < full; ++it) {
      int sn = __shfl(my, 2 * it + half);
      u16x8 v = *(const u16x8*)&xp[(size_t)sn * 256 + l32 * 8];
#pragma unroll
      for (int k = 0; k < 8; ++k) a[k] += b2f(v[k]);
    }
    if (cnt & 1) {
      int sn = __shfl(my, cnt - 1);
      if (half == 0) {
        u16x8 v = *(const u16x8*)&xp[(size_t)sn * 256 + l32 * 8];
#pragma unroll
        for (int k = 0; k < 8; ++k) a[k] += b2f(v[k]);
      }
    }
  }
  // combine even/odd halves (partner lane ^ 32)
#pragma unroll
  for (int k = 0; k < 8; ++k) a[k] += __shfl_xor(a[k], 32);

  int c = e - s; if (c < 1) c = 1;
  float inv = 1.f / (float)c;
  if (half == 0) {
    u16x8 o;
#pragma unroll
    for (int k = 0; k < 8; ++k) o[k] = f2b(a[k] * inv);
    *(u16x8*)&mean[(size_t)node * 256 + l32 * 8] = o;   // 32 lanes x 16B = 512B
  }
}

// ---------------- MFMA GEMM: C = act(A1@B1^T + A2@B2^T + bias) ----------------
#define GLD16(g, l) \
  __builtin_amdgcn_global_load_lds((const __attribute__((address_space(1))) void*)(g), \
                                   (__attribute__((address_space(3))) void*)(l), 16, 0, 0)

__global__ __launch_bounds__(256, 2)
void gemm_bf16(const ushort* __restrict__ A1, const ushort* __restrict__ B1,
               const ushort* __restrict__ A2, const ushort* __restrict__ B2,
               const ushort* __restrict__ bias, ushort* __restrict__ C,
               float* __restrict__ Cf, const int* __restrict__ flag,
               int M, int N, int K1, int K2, int do_relu) {
  __shared__ __align__(16) ushort lsA[128 * 32];
  __shared__ __align__(16) ushort lsB[128 * 32];
  const int tid = threadIdx.x;
  const int lane = tid & 63;
  const int wid = tid >> 6;
  const int wr = wid >> 1, wc = wid & 1;
  const int m0 = blockIdx.x * 128;
  const int n0 = blockIdx.y * 128;
  const int l15 = lane & 15;
  const int lg = lane >> 4;
  const int fl = Cf ? *flag : 0;

  f32x4 acc[4][4];
#pragma unroll
  for (int i = 0; i < 4; ++i)
#pragma unroll
    for (int j = 0; j < 4; ++j) {
      acc[i][j][0] = 0.f; acc[i][j][1] = 0.f; acc[i][j][2] = 0.f; acc[i][j][3] = 0.f;
    }

#pragma unroll
  for (int pass = 0; pass < 2; ++pass) {
    const ushort* A = pass ? A2 : A1;
    const ushort* B = pass ? B2 : B1;
    const int K = pass ? K2 : K1;
    if (K == 0) continue;
    for (int k0 = 0; k0 < K; k0 += 32) {
#pragma unroll
      for (int it = 0; it < 2; ++it) {
        int o = tid * 16 + it * 4096;   // byte offset within 8KB tile
        int row = o >> 6;               // 64 bytes per row
        int colb = o & 63;
        const ushort* ga = A + (size_t)(m0 + row) * K + k0 + (colb >> 1);
        GLD16(ga, (char*)lsA + o);
        const ushort* gb = B + (size_t)(n0 + row) * K + k0 + (colb >> 1);
        GLD16(gb, (char*)lsB + o);
      }
      __syncthreads();
      s16x8 af[4], bfr[4];
#pragma unroll
      for (int i = 0; i < 4; ++i)
        af[i] = *(const s16x8*)&lsA[(wr * 64 + i * 16 + l15) * 32 + lg * 8];
#pragma unroll
      for (int j = 0; j < 4; ++j)
        bfr[j] = *(const s16x8*)&lsB[(wc * 64 + j * 16 + l15) * 32 + lg * 8];
#pragma unroll
      for (int i = 0; i < 4; ++i)
#pragma unroll
        for (int j = 0; j < 4; ++j)
          acc[i][j] = __builtin_amdgcn_mfma_f32_16x16x32_bf16(af[i], bfr[j], acc[i][j], 0, 0, 0);
      __syncthreads();
    }
  }

#pragma unroll
  for (int j = 0; j < 4; ++j) {
    int col = n0 + wc * 64 + j * 16 + l15;
    float bv = bias ? b2f(bias[col]) : 0.f;
#pragma unroll
    for (int i = 0; i < 4; ++i) {
      int rbase = m0 + wr * 64 + i * 16 + lg * 4;
#pragma unroll
      for (int r = 0; r < 4; ++r) {
        float v = acc[i][j][r] + bv;
        if (do_relu) v = fmaxf(v, 0.f);
        size_t idx = (size_t)(rbase + r) * N + col;
        if (Cf) {
          if (fl) Cf[idx] = v;
          else    C[idx] = f2b(v);
        } else {
          C[idx] = f2b(v);
        }
      }
    }
  }
}

// ---------------- kriging gather (reads dual-dtype h region of d_out) ----------------
__global__ void gather_out(const ushort* __restrict__ hb, const float* __restrict__ hf,
                           const int* __restrict__ map_id, void* __restrict__ dout,
                           const int* __restrict__ flag,
                           int K, int num_nodes, int total, int N) {
  int i = blockIdx.x * 256 + threadIdx.x;
  if (i >= total) return;
  int f = i & 127;
  int row = i >> 7;
  int b = row / K;
  unsigned node = (unsigned)(b * num_nodes + map_id[row]);
  bool ok = node < (unsigned)N;
  if (*flag) {
    ((float*)dout)[i] = ok ? hf[(size_t)node * 128 + f] : 0.f;
  } else {
    ((ushort*)dout)[i] = ok ? hb[(size_t)node * 128 + f] : (ushort)0;
  }
}

extern "C" void kernel_launch(void* const* d_in, const int* in_sizes, int n_in,
                              void* d_out, int out_size, void* d_ws, size_t ws_size,
                              hipStream_t stream) {
  const void* x    = d_in[0];
  const int*  ei   = (const int*)d_in[1];
  const int*  mapi = (const int*)d_in[2];
  const void* Wp1  = d_in[4];
  const void* bp1  = d_in[5];
  const void* Wl1  = d_in[6];
  const void* bl1  = d_in[7];
  const void* Wr1  = d_in[8];
  const void* Wp2  = d_in[9];
  const void* bp2  = d_in[10];
  const void* Wl2  = d_in[11];
  const void* bl2  = d_in[12];
  const void* Wr2  = d_in[13];
  const void* Wlin = d_in[14];
  const void* blin = d_in[15];

  const int NN = in_sizes[0] / 256;   // 80000
  const int E  = in_sizes[1] / 2;     // 1.28M
  const int MAPROWS = in_sizes[2];    // 40000
  const int BS = 16;
  const int NUM_NODES = NN / BS;      // 5000
  const int KMAP = MAPROWS / BS;      // 2500
  const int* src = ei;
  const int* dst = ei + E;

  // h output region inside d_out (element offset MAPROWS*128, dtype-dependent base)
  ushort* houtB = (ushort*)d_out + (size_t)MAPROWS * 128;
  float*  houtF = (float*)d_out + (size_t)MAPROWS * 128;

  // ---- small scratch in d_out's local_feat region (dead until final gather) ----
  char* sc = (char*)d_out;
  auto carve_sc = [&](size_t bytes) {
    char* p = sc; sc += (bytes + 255) & ~(size_t)255; return p;
  };
  ushort* Wp1T  = (ushort*)carve_sc(256 * 256 * 2);
  ushort* Wl1T  = (ushort*)carve_sc(256 * 256 * 2);
  ushort* Wr1T  = (ushort*)carve_sc(256 * 256 * 2);
  ushort* Wp2T  = (ushort*)carve_sc(256 * 256 * 2);
  ushort* Wl2T  = (ushort*)carve_sc(128 * 256 * 2);
  ushort* Wr2T  = (ushort*)carve_sc(128 * 256 * 2);
  ushort* WlinT = (ushort*)carve_sc(128 * 128 * 2);
  ushort* bp1c  = (ushort*)carve_sc(256 * 2);
  ushort* bl1c  = (ushort*)carve_sc(256 * 2);
  ushort* bp2c  = (ushort*)carve_sc(256 * 2);
  ushort* bl2c  = (ushort*)carve_sc(128 * 2);
  ushort* blinc = (ushort*)carve_sc(128 * 2);
  int* deg    = (int*)carve_sc((size_t)NN * 4);
  int* rowptr = (int*)carve_sc(((size_t)NN + 1) * 4);
  int* pos    = (int*)carve_sc((size_t)NN * 4);
  int* eidx   = (int*)carve_sc((size_t)E * 4);
  int* bsum   = (int*)carve_sc(1024);
  int* ebsum  = (int*)carve_sc(1024);

  // ---- big buffers in d_ws: flag + 3 x 40.96MB ----
  char* w = (char*)d_ws;
  auto carve = [&](size_t bytes) {
    char* p = w; w += (bytes + 255) & ~(size_t)255; return p;
  };
  int*    flag = (int*)carve(256);
  ushort* xb   = (ushort*)carve((size_t)NN * 256 * 2);  // x_bf16 -> mean2
  ushort* bA   = (ushort*)carve((size_t)NN * 256 * 2);  // xp1 -> h1
  ushort* bB   = (ushort*)carve((size_t)NN * 256 * 2);  // mean1 -> xp2 -> h2

  // --- dtype detect + conversions ---
  detect_dtype<<<dim3(1), 256, 0, stream>>>((const ushort*)x, flag);
  convert_x<<<dim3((NN * 256 / 4 + 255) / 256), 256, 0, stream>>>(x, xb, flag, NN * 256);

  WPack wp;
  wp.d[0] = {Wp1, Wp1T, 256, 256};
  wp.d[1] = {Wl1, Wl1T, 256, 256};
  wp.d[2] = {Wr1, Wr1T, 256, 256};
  wp.d[3] = {Wp2, Wp2T, 256, 256};
  wp.d[4] = {Wl2, Wl2T, 256, 128};
  wp.d[5] = {Wr2, Wr2T, 256, 128};
  wp.d[6] = {Wlin, WlinT, 128, 128};
  transpose_convert_all<<<dim3(256, 7), 256, 0, stream>>>(wp, flag);

  BPack bp;
  bp.d[0] = {bp1, bp1c, 256, 1};
  bp.d[1] = {bl1, bl1c, 256, 1};
  bp.d[2] = {bp2, bp2c, 256, 1};
  bp.d[3] = {bl2, bl2c, 128, 1};
  bp.d[4] = {blin, blinc, 128, 1};
  convert_vec_all<<<dim3(1, 5), 256, 0, stream>>>(bp, flag);

  // --- CSR build ---
  hipMemsetAsync(deg, 0, (size_t)NN * 4, stream);
  hist_kernel<<<dim3((E + 255) / 256), 256, 0, stream>>>(dst, deg, E, NN);
  int SB = (NN + 1023) / 1024;   // 79 scan blocks (<=256 supported)
  scan_phaseA<<<dim3(SB), 256, 0, stream>>>(deg, bsum, NN);
  scan_phaseB<<<dim3(1), 256, 0, stream>>>(bsum, ebsum, rowptr, SB, NN);
  scan_phaseC<<<dim3(SB), 256, 0, stream>>>(deg, ebsum, rowptr, pos, NN);
  scatter_kernel<<<dim3((E + 255) / 256), 256, 0, stream>>>(src, dst, pos, eidx, E, NN);

  dim3 blk(256);
  dim3 g256(NN / 128, 2);   // N=256
  dim3 g128(NN / 128, 1);   // N=128
  dim3 gagg((NN + 3) / 4);

  // --- layer 1 ---
  gemm_bf16<<<g256, blk, 0, stream>>>(xb, Wp1T, nullptr, nullptr, bp1c, bA,
                                      nullptr, nullptr, NN, 256, 256, 0, 1);        // xp1
  agg_mean_v3<<<gagg, blk, 0, stream>>>(bA, rowptr, eidx, bB, NN);                  // mean1
  gemm_bf16<<<g256, blk, 0, stream>>>(bB, Wl1T, xb, Wr1T, bl1c, bA,
                                      nullptr, nullptr, NN, 256, 256, 256, 1);      // h1

  // --- layer 2 ---
  gemm_bf16<<<g256, blk, 0, stream>>>(bA, Wp2T, nullptr, nullptr, bp2c, bB,
                                      nullptr, nullptr, NN, 256, 256, 0, 1);        // xp2
  agg_mean_v3<<<gagg, blk, 0, stream>>>(bB, rowptr, eidx, xb, NN);                  // mean2
  gemm_bf16<<<g128, blk, 0, stream>>>(xb, Wl2T, bA, Wr2T, bl2c, bB,
                                      nullptr, nullptr, NN, 128, 256, 256, 1);      // h2

  // --- final linear: write dual-dtype h straight into d_out h region ---
  gemm_bf16<<<g128, blk, 0, stream>>>(bB, WlinT, nullptr, nullptr, blinc, houtB,
                                      houtF, flag, NN, 128, 128, 0, 0);

  // --- kriging gather -> d_out local_feat region (overwrites scratch, last use) ---
  int total = MAPROWS * 128;
  gather_out<<<dim3((total + 255) / 256), 256, 0, stream>>>(houtB, houtF, mapi, d_out,
                                                            flag, KMAP, NUM_NODES, total, NN);
}

// Round 7
// 513.658 us; speedup vs baseline: 2.0321x; 1.0302x over previous
//
#include <hip/hip_runtime.h>
#include <hip/hip_bf16.h>

typedef __attribute__((ext_vector_type(8))) short s16x8;
typedef __attribute__((ext_vector_type(8))) ushort u16x8;
typedef __attribute__((ext_vector_type(4))) float f32x4;

static __device__ __forceinline__ float b2f(ushort u) {
  union { float f; unsigned bits; } v; v.bits = ((unsigned)u) << 16; return v.f;
}
static __device__ __forceinline__ ushort f2b(float f) {
  __hip_bfloat16 h = __float2bfloat16(f);
  return *reinterpret_cast<ushort*>(&h);
}

// ---------------- dtype detector ----------------
// flag: 1 = inputs are f32, 0 = inputs are bf16.
__global__ void detect_dtype(const ushort* __restrict__ xraw, int* __restrict__ flag) {
  __shared__ int cnt;
  if (threadIdx.x == 0) cnt = 0;
  __syncthreads();
  ushort u = xraw[threadIdx.x];
  int e = (u >> 7) & 0xFF;
  if (e >= 113 && e <= 141) atomicAdd(&cnt, 1);
  __syncthreads();
  if (threadIdx.x == 0) *flag = (cnt >= 224) ? 0 : 1;
}

// ---------------- input conversion (dual path) ----------------
__global__ void convert_x(const void* __restrict__ xin, ushort* __restrict__ xb,
                          const int* __restrict__ flag, int n) {
  int i = blockIdx.x * 256 + threadIdx.x;   // handles 4 elements
  int base = i * 4;
  if (base >= n) return;
  if (*flag) {
    const float4 v = ((const float4*)xin)[i];
    xb[base + 0] = f2b(v.x); xb[base + 1] = f2b(v.y);
    xb[base + 2] = f2b(v.z); xb[base + 3] = f2b(v.w);
  } else {
    ((ushort4*)xb)[i] = ((const ushort4*)xin)[i];
  }
}

// ---------------- batched weight transpose+convert (7 matrices, 1 launch) ----------------
struct WDesc { const void* src; ushort* dst; int R, C; };
struct WPack { WDesc d[7]; };

__global__ void transpose_convert_all(WPack p, const int* __restrict__ flag) {
  const WDesc& d = p.d[blockIdx.y];
  int i = blockIdx.x * 256 + threadIdx.x;
  if (i >= d.R * d.C) return;
  int r = i / d.C, c = i % d.C;
  ushort v = (*flag) ? f2b(((const float*)d.src)[i]) : ((const ushort*)d.src)[i];
  d.dst[c * d.R + r] = v;
}

// ---------------- batched bias convert (5 vectors, 1 launch) ----------------
struct BPack { WDesc d[5]; };
__global__ void convert_vec_all(BPack p, const int* __restrict__ flag) {
  const WDesc& d = p.d[blockIdx.y];
  int i = threadIdx.x;
  if (i >= d.R) return;
  d.dst[i] = (*flag) ? f2b(((const float*)d.src)[i]) : ((const ushort*)d.src)[i];
}

// ---------------- CSR build (two-level counting sort) ----------------
// Bucket = dst >> 9 (512 nodes/bucket). NBUCK <= 512.

// per-node degree + per-bucket counts (LDS histogram, 2048 edges/block)
__global__ __launch_bounds__(256)
void hist_bucket_kernel(const int* __restrict__ dst, int* __restrict__ deg,
                        int* __restrict__ bcnt, int E, int N, int nbuck) {
  __shared__ int lh[512];
  int t = threadIdx.x;
  for (int i = t; i < nbuck; i += 256) lh[i] = 0;
  __syncthreads();
  int base = blockIdx.x * 2048;
#pragma unroll
  for (int k = 0; k < 8; ++k) {
    int e = base + k * 256 + t;
    if (e < E) {
      unsigned d = (unsigned)dst[e];
      if (d < (unsigned)N) {
        atomicAdd(&deg[d], 1);
        atomicAdd(&lh[d >> 9], 1);
      }
    }
  }
  __syncthreads();
  for (int i = t; i < nbuck; i += 256)
    if (lh[i]) atomicAdd(&bcnt[i], lh[i]);
}

// exclusive scan of bucket counts (1 block; nbuck <= 256)
__global__ __launch_bounds__(256)
void scan_buckets(const int* __restrict__ bcnt, int* __restrict__ bscan,
                  int* __restrict__ bpos, int nbuck) {
  int t = threadIdx.x;
  __shared__ int sh[256];
  int v = (t < nbuck) ? bcnt[t] : 0;
  sh[t] = v; __syncthreads();
  for (int off = 1; off < 256; off <<= 1) {
    int u = (t >= off) ? sh[t - off] : 0;
    __syncthreads();
    sh[t] += u;
    __syncthreads();
  }
  if (t < nbuck) { int ex = sh[t] - v; bscan[t] = ex; bpos[t] = ex; }
  if (t == nbuck - 1) bscan[nbuck] = sh[t];
}

// bin edges into bucket-grouped (src,dst) pairs; radix-pass structure
__global__ __launch_bounds__(256)
void bin_scatter(const int* __restrict__ src, const int* __restrict__ dstl,
                 int* __restrict__ bpos, int2* __restrict__ pairs,
                 int E, int N, int nbuck) {
  __shared__ int lh[512];
  __shared__ int lbase[512];
  int t = threadIdx.x;
  for (int i = t; i < nbuck; i += 256) lh[i] = 0;
  __syncthreads();
  int base = blockIdx.x * 4096;
#pragma unroll
  for (int k = 0; k < 16; ++k) {
    int e = base + k * 256 + t;
    if (e < E) {
      unsigned d = (unsigned)dstl[e];
      if (d < (unsigned)N) atomicAdd(&lh[d >> 9], 1);
    }
  }
  __syncthreads();
  for (int i = t; i < nbuck; i += 256) {
    int c = lh[i];
    lbase[i] = c ? atomicAdd(&bpos[i], c) : 0;
    lh[i] = 0;
  }
  __syncthreads();
#pragma unroll
  for (int k = 0; k < 16; ++k) {
    int e = base + k * 256 + t;
    if (e < E) {
      unsigned d = (unsigned)dstl[e];
      if (d < (unsigned)N) {
        int b = d >> 9;
        int r = atomicAdd(&lh[b], 1);
        pairs[lbase[b] + r] = make_int2(src[e], (int)d);
      }
    }
  }
}

// per-bucket scatter into final eidx (pos/eidx windows stay cache-hot)
#define FS_SPLIT 4
__global__ __launch_bounds__(256)
void final_scatter(const int2* __restrict__ pairs, const int* __restrict__ bscan,
                   int* __restrict__ pos, int* __restrict__ eidx, int E) {
  int b = blockIdx.x / FS_SPLIT;
  int part = blockIdx.x % FS_SPLIT;
  int s = bscan[b], e = bscan[b + 1];
  int len = e - s;
  int per = (len + FS_SPLIT - 1) / FS_SPLIT;
  int lo = s + part * per;
  int hi = min(lo + per, e);
  for (int i = lo + threadIdx.x; i < hi; i += 256) {
    int2 p = pairs[i];
    unsigned q = (unsigned)atomicAdd(&pos[p.y], 1);
    if (q < (unsigned)E) eidx[q] = p.x;
  }
}

// 3-phase device-wide exclusive scan of deg -> rowptr/pos
__global__ __launch_bounds__(256)
void scan_phaseA(const int* __restrict__ deg, int* __restrict__ bsum, int N) {
  int b = blockIdx.x, t = threadIdx.x;
  int i0 = b * 1024 + t * 4;
  int s = 0;
#pragma unroll
  for (int k = 0; k < 4; ++k) {
    int i = i0 + k;
    if (i < N) s += deg[i];
  }
  __shared__ int red[256];
  red[t] = s; __syncthreads();
  for (int off = 128; off > 0; off >>= 1) {
    if (t < off) red[t] += red[t + off];
    __syncthreads();
  }
  if (t == 0) bsum[b] = red[0];
}

__global__ __launch_bounds__(256)
void scan_phaseB(const int* __restrict__ bsum, int* __restrict__ ebsum,
                 int* __restrict__ rowptr, int B, int N) {
  int t = threadIdx.x;
  __shared__ int sh[256];
  int v = (t < B) ? bsum[t] : 0;
  sh[t] = v; __syncthreads();
  for (int off = 1; off < 256; off <<= 1) {
    int u = (t >= off) ? sh[t - off] : 0;
    __syncthreads();
    sh[t] += u;
    __syncthreads();
  }
  if (t < B) ebsum[t] = sh[t] - v;
  if (t == B - 1) rowptr[N] = sh[t];
}

__global__ __launch_bounds__(256)
void scan_phaseC(const int* __restrict__ deg, const int* __restrict__ ebsum,
                 int* __restrict__ rowptr, int* __restrict__ pos, int N) {
  int b = blockIdx.x, t = threadIdx.x;
  int i0 = b * 1024 + t * 4;
  int v[4]; int s = 0;
#pragma unroll
  for (int k = 0; k < 4; ++k) {
    int i = i0 + k;
    v[k] = (i < N) ? deg[i] : 0;
    s += v[k];
  }
  __shared__ int sh[256];
  sh[t] = s; __syncthreads();
  for (int off = 1; off < 256; off <<= 1) {
    int u = (t >= off) ? sh[t - off] : 0;
    __syncthreads();
    sh[t] += u;
    __syncthreads();
  }
  int run = ebsum[b] + sh[t] - s;
#pragma unroll
  for (int k = 0; k < 4; ++k) {
    int i = i0 + k;
    if (i < N) { rowptr[i] = run; pos[i] = run; run += v[k]; }
  }
}

// ---------------- mean aggregation v3 (wave-per-node, 16B/lane, 2 rows/load) ----------------
__global__ __launch_bounds__(256)
void agg_mean_v3(const ushort* __restrict__ xp, const int* __restrict__ rowptr,
                 const int* __restrict__ eidx, ushort* __restrict__ mean, int NN) {
  int node = blockIdx.x * 4 + (threadIdx.x >> 6);
  if (node >= NN) return;
  int lane = threadIdx.x & 63;
  int half = lane >> 5;        // 0 = even neighbor, 1 = odd neighbor
  int l32 = lane & 31;         // feature block: features l32*8 .. +7
  int s = rowptr[node], e = rowptr[node + 1];
  float a[8];
#pragma unroll
  for (int k = 0; k < 8; ++k) a[k] = 0.f;

  for (int base = s; base < e; base += 64) {
    int cnt = min(64, e - base);
    int my = (lane < cnt) ? eidx[base + lane] : 0;
    int full = cnt >> 1;
#pragma unroll 2
    for (int it = 0; it < full; ++it) {
      int sn = __shfl(my, 2 * it + half);
      u16x8 v = *(const u16x8*)&xp[(size_t)sn * 256 + l32 * 8];
#pragma unroll
      for (int k = 0; k < 8; ++k) a[k] += b2f(v[k]);
    }
    if (cnt & 1) {
      int sn = __shfl(my, cnt - 1);
      if (half == 0) {
        u16x8 v = *(const u16x8*)&xp[(size_t)sn * 256 + l32 * 8];
#pragma unroll
        for (int k = 0; k < 8; ++k) a[k] += b2f(v[k]);
      }
    }
  }
#pragma unroll
  for (int k = 0; k < 8; ++k) a[k] += __shfl_xor(a[k], 32);

  int c = e - s; if (c < 1) c = 1;
  float inv = 1.f / (float)c;
  if (half == 0) {
    u16x8 o;
#pragma unroll
    for (int k = 0; k < 8; ++k) o[k] = f2b(a[k] * inv);
    *(u16x8*)&mean[(size_t)node * 256 + l32 * 8] = o;
  }
}

// ---------------- MFMA GEMM: C = act(A1@B1^T + A2@B2^T + bias) ----------------
#define GLD16(g, l) \
  __builtin_amdgcn_global_load_lds((const __attribute__((address_space(1))) void*)(g), \
                                   (__attribute__((address_space(3))) void*)(l), 16, 0, 0)

__global__ __launch_bounds__(256, 2)
void gemm_bf16(const ushort* __restrict__ A1, const ushort* __restrict__ B1,
               const ushort* __restrict__ A2, const ushort* __restrict__ B2,
               const ushort* __restrict__ bias, ushort* __restrict__ C,
               float* __restrict__ Cf, const int* __restrict__ flag,
               int M, int N, int K1, int K2, int do_relu) {
  __shared__ __align__(16) ushort lsA[128 * 32];
  __shared__ __align__(16) ushort lsB[128 * 32];
  const int tid = threadIdx.x;
  const int lane = tid & 63;
  const int wid = tid >> 6;
  const int wr = wid >> 1, wc = wid & 1;
  const int m0 = blockIdx.x * 128;
  const int n0 = blockIdx.y * 128;
  const int l15 = lane & 15;
  const int lg = lane >> 4;
  const int fl = Cf ? *flag : 0;

  f32x4 acc[4][4];
#pragma unroll
  for (int i = 0; i < 4; ++i)
#pragma unroll
    for (int j = 0; j < 4; ++j) {
      acc[i][j][0] = 0.f; acc[i][j][1] = 0.f; acc[i][j][2] = 0.f; acc[i][j][3] = 0.f;
    }

#pragma unroll
  for (int pass = 0; pass < 2; ++pass) {
    const ushort* A = pass ? A2 : A1;
    const ushort* B = pass ? B2 : B1;
    const int K = pass ? K2 : K1;
    if (K == 0) continue;
    for (int k0 = 0; k0 < K; k0 += 32) {
#pragma unroll
      for (int it = 0; it < 2; ++it) {
        int o = tid * 16 + it * 4096;   // byte offset within 8KB tile
        int row = o >> 6;               // 64 bytes per row
        int colb = o & 63;
        const ushort* ga = A + (size_t)(m0 + row) * K + k0 + (colb >> 1);
        GLD16(ga, (char*)lsA + o);
        const ushort* gb = B + (size_t)(n0 + row) * K + k0 + (colb >> 1);
        GLD16(gb, (char*)lsB + o);
      }
      __syncthreads();
      s16x8 af[4], bfr[4];
#pragma unroll
      for (int i = 0; i < 4; ++i)
        af[i] = *(const s16x8*)&lsA[(wr * 64 + i * 16 + l15) * 32 + lg * 8];
#pragma unroll
      for (int j = 0; j < 4; ++j)
        bfr[j] = *(const s16x8*)&lsB[(wc * 64 + j * 16 + l15) * 32 + lg * 8];
#pragma unroll
      for (int i = 0; i < 4; ++i)
#pragma unroll
        for (int j = 0; j < 4; ++j)
          acc[i][j] = __builtin_amdgcn_mfma_f32_16x16x32_bf16(af[i], bfr[j], acc[i][j], 0, 0, 0);
      __syncthreads();
    }
  }

#pragma unroll
  for (int j = 0; j < 4; ++j) {
    int col = n0 + wc * 64 + j * 16 + l15;
    float bv = bias ? b2f(bias[col]) : 0.f;
#pragma unroll
    for (int i = 0; i < 4; ++i) {
      int rbase = m0 + wr * 64 + i * 16 + lg * 4;
#pragma unroll
      for (int r = 0; r < 4; ++r) {
        float v = acc[i][j][r] + bv;
        if (do_relu) v = fmaxf(v, 0.f);
        size_t idx = (size_t)(rbase + r) * N + col;
        if (Cf) {
          if (fl) Cf[idx] = v;
          else    C[idx] = f2b(v);
        } else {
          C[idx] = f2b(v);
        }
      }
    }
  }
}

// ---------------- kriging gather (reads dual-dtype h region of d_out) ----------------
__global__ void gather_out(const ushort* __restrict__ hb, const float* __restrict__ hf,
                           const int* __restrict__ map_id, void* __restrict__ dout,
                           const int* __restrict__ flag,
                           int K, int num_nodes, int total, int N) {
  int i = blockIdx.x * 256 + threadIdx.x;
  if (i >= total) return;
  int f = i & 127;
  int row = i >> 7;
  int b = row / K;
  unsigned node = (unsigned)(b * num_nodes + map_id[row]);
  bool ok = node < (unsigned)N;
  if (*flag) {
    ((float*)dout)[i] = ok ? hf[(size_t)node * 128 + f] : 0.f;
  } else {
    ((ushort*)dout)[i] = ok ? hb[(size_t)node * 128 + f] : (ushort)0;
  }
}

extern "C" void kernel_launch(void* const* d_in, const int* in_sizes, int n_in,
                              void* d_out, int out_size, void* d_ws, size_t ws_size,
                              hipStream_t stream) {
  const void* x    = d_in[0];
  const int*  ei   = (const int*)d_in[1];
  const int*  mapi = (const int*)d_in[2];
  const void* Wp1  = d_in[4];
  const void* bp1  = d_in[5];
  const void* Wl1  = d_in[6];
  const void* bl1  = d_in[7];
  const void* Wr1  = d_in[8];
  const void* Wp2  = d_in[9];
  const void* bp2  = d_in[10];
  const void* Wl2  = d_in[11];
  const void* bl2  = d_in[12];
  const void* Wr2  = d_in[13];
  const void* Wlin = d_in[14];
  const void* blin = d_in[15];

  const int NN = in_sizes[0] / 256;   // 80000
  const int E  = in_sizes[1] / 2;     // 1.28M
  const int MAPROWS = in_sizes[2];    // 40000
  const int BS = 16;
  const int NUM_NODES = NN / BS;      // 5000
  const int KMAP = MAPROWS / BS;      // 2500
  const int NBUCK = (NN + 511) >> 9;  // 157 buckets of 512 nodes
  const int* src = ei;
  const int* dst = ei + E;

  // h output region inside d_out (element offset MAPROWS*128, dtype-dependent base)
  ushort* houtB = (ushort*)d_out + (size_t)MAPROWS * 128;
  float*  houtF = (float*)d_out + (size_t)MAPROWS * 128;

  // pairs buffer: byte offset 2*MAPROWS*128*2 of d_out — inside the h region
  // under BOTH dtype interpretations; dead until the final GEMM writes h.
  int2* pairs = (int2*)((char*)d_out + (size_t)MAPROWS * 128 * 4);

  // ---- small scratch in d_out's local_feat region (dead until final gather) ----
  char* sc = (char*)d_out;
  auto carve_sc = [&](size_t bytes) {
    char* p = sc; sc += (bytes + 255) & ~(size_t)255; return p;
  };
  ushort* Wp1T  = (ushort*)carve_sc(256 * 256 * 2);
  ushort* Wl1T  = (ushort*)carve_sc(256 * 256 * 2);
  ushort* Wr1T  = (ushort*)carve_sc(256 * 256 * 2);
  ushort* Wp2T  = (ushort*)carve_sc(256 * 256 * 2);
  ushort* Wl2T  = (ushort*)carve_sc(128 * 256 * 2);
  ushort* Wr2T  = (ushort*)carve_sc(128 * 256 * 2);
  ushort* WlinT = (ushort*)carve_sc(128 * 128 * 2);
  ushort* bp1c  = (ushort*)carve_sc(256 * 2);
  ushort* bl1c  = (ushort*)carve_sc(256 * 2);
  ushort* bp2c  = (ushort*)carve_sc(256 * 2);
  ushort* bl2c  = (ushort*)carve_sc(128 * 2);
  ushort* blinc = (ushort*)carve_sc(128 * 2);
  int* deg    = (int*)carve_sc((size_t)NN * 4);
  int* rowptr = (int*)carve_sc(((size_t)NN + 1) * 4);
  int* pos    = (int*)carve_sc((size_t)NN * 4);
  int* eidx   = (int*)carve_sc((size_t)E * 4);
  int* bsum   = (int*)carve_sc(1024);
  int* ebsum  = (int*)carve_sc(1024);
  int* bcnt   = (int*)carve_sc(2048);
  int* bscan  = (int*)carve_sc(2048 + 4);
  int* bpos   = (int*)carve_sc(2048);

  // ---- big buffers in d_ws: flag + 3 x 40.96MB ----
  char* w = (char*)d_ws;
  auto carve = [&](size_t bytes) {
    char* p = w; w += (bytes + 255) & ~(size_t)255; return p;
  };
  int*    flag = (int*)carve(256);
  ushort* xb   = (ushort*)carve((size_t)NN * 256 * 2);  // x_bf16 -> mean2
  ushort* bA   = (ushort*)carve((size_t)NN * 256 * 2);  // xp1 -> h1
  ushort* bB   = (ushort*)carve((size_t)NN * 256 * 2);  // mean1 -> xp2 -> h2

  // --- dtype detect + conversions ---
  detect_dtype<<<dim3(1), 256, 0, stream>>>((const ushort*)x, flag);
  convert_x<<<dim3((NN * 256 / 4 + 255) / 256), 256, 0, stream>>>(x, xb, flag, NN * 256);

  WPack wp;
  wp.d[0] = {Wp1, Wp1T, 256, 256};
  wp.d[1] = {Wl1, Wl1T, 256, 256};
  wp.d[2] = {Wr1, Wr1T, 256, 256};
  wp.d[3] = {Wp2, Wp2T, 256, 256};
  wp.d[4] = {Wl2, Wl2T, 256, 128};
  wp.d[5] = {Wr2, Wr2T, 256, 128};
  wp.d[6] = {Wlin, WlinT, 128, 128};
  transpose_convert_all<<<dim3(256, 7), 256, 0, stream>>>(wp, flag);

  BPack bp;
  bp.d[0] = {bp1, bp1c, 256, 1};
  bp.d[1] = {bl1, bl1c, 256, 1};
  bp.d[2] = {bp2, bp2c, 256, 1};
  bp.d[3] = {bl2, bl2c, 128, 1};
  bp.d[4] = {blin, blinc, 128, 1};
  convert_vec_all<<<dim3(1, 5), 256, 0, stream>>>(bp, flag);

  // --- CSR build (two-level counting sort) ---
  hipMemsetAsync(deg, 0, (size_t)NN * 4, stream);
  hipMemsetAsync(bcnt, 0, 2048, stream);
  hist_bucket_kernel<<<dim3((E + 2047) / 2048), 256, 0, stream>>>(dst, deg, bcnt, E, NN, NBUCK);
  scan_buckets<<<dim3(1), 256, 0, stream>>>(bcnt, bscan, bpos, NBUCK);
  int SB = (NN + 1023) / 1024;
  scan_phaseA<<<dim3(SB), 256, 0, stream>>>(deg, bsum, NN);
  scan_phaseB<<<dim3(1), 256, 0, stream>>>(bsum, ebsum, rowptr, SB, NN);
  scan_phaseC<<<dim3(SB), 256, 0, stream>>>(deg, ebsum, rowptr, pos, NN);
  bin_scatter<<<dim3((E + 4095) / 4096), 256, 0, stream>>>(src, dst, bpos, pairs, E, NN, NBUCK);
  final_scatter<<<dim3(NBUCK * FS_SPLIT), 256, 0, stream>>>(pairs, bscan, pos, eidx, E);

  dim3 blk(256);
  dim3 g256(NN / 128, 2);   // N=256
  dim3 g128(NN / 128, 1);   // N=128
  dim3 gagg((NN + 3) / 4);

  // --- layer 1 ---
  gemm_bf16<<<g256, blk, 0, stream>>>(xb, Wp1T, nullptr, nullptr, bp1c, bA,
                                      nullptr, nullptr, NN, 256, 256, 0, 1);        // xp1
  agg_mean_v3<<<gagg, blk, 0, stream>>>(bA, rowptr, eidx, bB, NN);                  // mean1
  gemm_bf16<<<g256, blk, 0, stream>>>(bB, Wl1T, xb, Wr1T, bl1c, bA,
                                      nullptr, nullptr, NN, 256, 256, 256, 1);      // h1

  // --- layer 2 ---
  gemm_bf16<<<g256, blk, 0, stream>>>(bA, Wp2T, nullptr, nullptr, bp2c, bB,
                                      nullptr, nullptr, NN, 256, 256, 0, 1);        // xp2
  agg_mean_v3<<<gagg, blk, 0, stream>>>(bB, rowptr, eidx, xb, NN);                  // mean2
  gemm_bf16<<<g128, blk, 0, stream>>>(xb, Wl2T, bA, Wr2T, bl2c, bB,
                                      nullptr, nullptr, NN, 128, 256, 256, 1);      // h2

  // --- final linear: write dual-dtype h straight into d_out h region ---
  gemm_bf16<<<g128, blk, 0, stream>>>(bB, WlinT, nullptr, nullptr, blinc, houtB,
                                      houtF, flag, NN, 128, 128, 0, 0);

  // --- kriging gather -> d_out local_feat region (overwrites scratch, last use) ---
  int total = MAPROWS * 128;
  gather_out<<<dim3((total + 255) / 256), 256, 0, stream>>>(houtB, houtF, mapi, d_out,
                                                            flag, KMAP, NUM_NODES, total, NN);
}

// Round 8
// 510.332 us; speedup vs baseline: 2.0453x; 1.0065x over previous
//
#include <hip/hip_runtime.h>
#include <hip/hip_bf16.h>

typedef __attribute__((ext_vector_type(8))) short s16x8;
typedef __attribute__((ext_vector_type(8))) ushort u16x8;
typedef __attribute__((ext_vector_type(4))) float f32x4;

static __device__ __forceinline__ float b2f(ushort u) {
  union { float f; unsigned bits; } v; v.bits = ((unsigned)u) << 16; return v.f;
}
static __device__ __forceinline__ ushort f2b(float f) {
  __hip_bfloat16 h = __float2bfloat16(f);
  return *reinterpret_cast<ushort*>(&h);
}

// ---------------- dtype detector ----------------
// flag: 1 = inputs are f32, 0 = inputs are bf16.
__global__ void detect_dtype(const ushort* __restrict__ xraw, int* __restrict__ flag) {
  __shared__ int cnt;
  if (threadIdx.x == 0) cnt = 0;
  __syncthreads();
  ushort u = xraw[threadIdx.x];
  int e = (u >> 7) & 0xFF;
  if (e >= 113 && e <= 141) atomicAdd(&cnt, 1);
  __syncthreads();
  if (threadIdx.x == 0) *flag = (cnt >= 224) ? 0 : 1;
}

// ---------------- input conversion (dual path) ----------------
__global__ void convert_x(const void* __restrict__ xin, ushort* __restrict__ xb,
                          const int* __restrict__ flag, int n) {
  int i = blockIdx.x * 256 + threadIdx.x;   // handles 4 elements
  int base = i * 4;
  if (base >= n) return;
  if (*flag) {
    const float4 v = ((const float4*)xin)[i];
    xb[base + 0] = f2b(v.x); xb[base + 1] = f2b(v.y);
    xb[base + 2] = f2b(v.z); xb[base + 3] = f2b(v.w);
  } else {
    ((ushort4*)xb)[i] = ((const ushort4*)xin)[i];
  }
}

// ---------------- batched weight transpose+convert (7 matrices, 1 launch) ----------------
struct WDesc { const void* src; ushort* dst; int R, C; };
struct WPack { WDesc d[7]; };

__global__ void transpose_convert_all(WPack p, const int* __restrict__ flag) {
  const WDesc& d = p.d[blockIdx.y];
  int i = blockIdx.x * 256 + threadIdx.x;
  if (i >= d.R * d.C) return;
  int r = i / d.C, c = i % d.C;
  ushort v = (*flag) ? f2b(((const float*)d.src)[i]) : ((const ushort*)d.src)[i];
  d.dst[c * d.R + r] = v;
}

// ---------------- batched bias convert (5 vectors, 1 launch) ----------------
struct BPack { WDesc d[5]; };
__global__ void convert_vec_all(BPack p, const int* __restrict__ flag) {
  const WDesc& d = p.d[blockIdx.y];
  int i = threadIdx.x;
  if (i >= d.R) return;
  d.dst[i] = (*flag) ? f2b(((const float*)d.src)[i]) : ((const ushort*)d.src)[i];
}

// ---------------- CSR build (two-level counting sort) ----------------
// Bucket = dst >> 9 (512 nodes/bucket). NBUCK <= 512.

__global__ __launch_bounds__(256)
void hist_bucket_kernel(const int* __restrict__ dst, int* __restrict__ deg,
                        int* __restrict__ bcnt, int E, int N, int nbuck) {
  __shared__ int lh[512];
  int t = threadIdx.x;
  for (int i = t; i < nbuck; i += 256) lh[i] = 0;
  __syncthreads();
  int base = blockIdx.x * 2048;
#pragma unroll
  for (int k = 0; k < 8; ++k) {
    int e = base + k * 256 + t;
    if (e < E) {
      unsigned d = (unsigned)dst[e];
      if (d < (unsigned)N) {
        atomicAdd(&deg[d], 1);
        atomicAdd(&lh[d >> 9], 1);
      }
    }
  }
  __syncthreads();
  for (int i = t; i < nbuck; i += 256)
    if (lh[i]) atomicAdd(&bcnt[i], lh[i]);
}

__global__ __launch_bounds__(256)
void scan_buckets(const int* __restrict__ bcnt, int* __restrict__ bscan,
                  int* __restrict__ bpos, int nbuck) {
  int t = threadIdx.x;
  __shared__ int sh[256];
  int v = (t < nbuck) ? bcnt[t] : 0;
  sh[t] = v; __syncthreads();
  for (int off = 1; off < 256; off <<= 1) {
    int u = (t >= off) ? sh[t - off] : 0;
    __syncthreads();
    sh[t] += u;
    __syncthreads();
  }
  if (t < nbuck) { int ex = sh[t] - v; bscan[t] = ex; bpos[t] = ex; }
  if (t == nbuck - 1) bscan[nbuck] = sh[t];
}

__global__ __launch_bounds__(256)
void bin_scatter(const int* __restrict__ src, const int* __restrict__ dstl,
                 int* __restrict__ bpos, int2* __restrict__ pairs,
                 int E, int N, int nbuck) {
  __shared__ int lh[512];
  __shared__ int lbase[512];
  int t = threadIdx.x;
  for (int i = t; i < nbuck; i += 256) lh[i] = 0;
  __syncthreads();
  int base = blockIdx.x * 4096;
#pragma unroll
  for (int k = 0; k < 16; ++k) {
    int e = base + k * 256 + t;
    if (e < E) {
      unsigned d = (unsigned)dstl[e];
      if (d < (unsigned)N) atomicAdd(&lh[d >> 9], 1);
    }
  }
  __syncthreads();
  for (int i = t; i < nbuck; i += 256) {
    int c = lh[i];
    lbase[i] = c ? atomicAdd(&bpos[i], c) : 0;
    lh[i] = 0;
  }
  __syncthreads();
#pragma unroll
  for (int k = 0; k < 16; ++k) {
    int e = base + k * 256 + t;
    if (e < E) {
      unsigned d = (unsigned)dstl[e];
      if (d < (unsigned)N) {
        int b = d >> 9;
        int r = atomicAdd(&lh[b], 1);
        pairs[lbase[b] + r] = make_int2(src[e], (int)d);
      }
    }
  }
}

#define FS_SPLIT 4
__global__ __launch_bounds__(256)
void final_scatter(const int2* __restrict__ pairs, const int* __restrict__ bscan,
                   int* __restrict__ pos, int* __restrict__ eidx, int E) {
  int b = blockIdx.x / FS_SPLIT;
  int part = blockIdx.x % FS_SPLIT;
  int s = bscan[b], e = bscan[b + 1];
  int len = e - s;
  int per = (len + FS_SPLIT - 1) / FS_SPLIT;
  int lo = s + part * per;
  int hi = min(lo + per, e);
  for (int i = lo + threadIdx.x; i < hi; i += 256) {
    int2 p = pairs[i];
    unsigned q = (unsigned)atomicAdd(&pos[p.y], 1);
    if (q < (unsigned)E) eidx[q] = p.x;
  }
}

// 3-phase device-wide exclusive scan of deg -> rowptr/pos
__global__ __launch_bounds__(256)
void scan_phaseA(const int* __restrict__ deg, int* __restrict__ bsum, int N) {
  int b = blockIdx.x, t = threadIdx.x;
  int i0 = b * 1024 + t * 4;
  int s = 0;
#pragma unroll
  for (int k = 0; k < 4; ++k) {
    int i = i0 + k;
    if (i < N) s += deg[i];
  }
  __shared__ int red[256];
  red[t] = s; __syncthreads();
  for (int off = 128; off > 0; off >>= 1) {
    if (t < off) red[t] += red[t + off];
    __syncthreads();
  }
  if (t == 0) bsum[b] = red[0];
}

__global__ __launch_bounds__(256)
void scan_phaseB(const int* __restrict__ bsum, int* __restrict__ ebsum,
                 int* __restrict__ rowptr, int B, int N) {
  int t = threadIdx.x;
  __shared__ int sh[256];
  int v = (t < B) ? bsum[t] : 0;
  sh[t] = v; __syncthreads();
  for (int off = 1; off < 256; off <<= 1) {
    int u = (t >= off) ? sh[t - off] : 0;
    __syncthreads();
    sh[t] += u;
    __syncthreads();
  }
  if (t < B) ebsum[t] = sh[t] - v;
  if (t == B - 1) rowptr[N] = sh[t];
}

__global__ __launch_bounds__(256)
void scan_phaseC(const int* __restrict__ deg, const int* __restrict__ ebsum,
                 int* __restrict__ rowptr, int* __restrict__ pos, int N) {
  int b = blockIdx.x, t = threadIdx.x;
  int i0 = b * 1024 + t * 4;
  int v[4]; int s = 0;
#pragma unroll
  for (int k = 0; k < 4; ++k) {
    int i = i0 + k;
    v[k] = (i < N) ? deg[i] : 0;
    s += v[k];
  }
  __shared__ int sh[256];
  sh[t] = s; __syncthreads();
  for (int off = 1; off < 256; off <<= 1) {
    int u = (t >= off) ? sh[t - off] : 0;
    __syncthreads();
    sh[t] += u;
    __syncthreads();
  }
  int run = ebsum[b] + sh[t] - s;
#pragma unroll
  for (int k = 0; k < 4; ++k) {
    int i = i0 + k;
    if (i < N) { rowptr[i] = run; pos[i] = run; run += v[k]; }
  }
}

// ---------------- mean aggregation v4 (wave-per-node, 4-deep load batching) ----------------
// lanes 0-31 even neighbors, 32-63 odd; each lane loads 16B (8 features).
// Inner loop issues 4 independent row-loads before accumulating (MLP=4).
__global__ __launch_bounds__(256)
void agg_mean_v4(const ushort* __restrict__ xp, const int* __restrict__ rowptr,
                 const int* __restrict__ eidx, ushort* __restrict__ mean, int NN) {
  int node = blockIdx.x * 4 + (threadIdx.x >> 6);
  if (node >= NN) return;
  int lane = threadIdx.x & 63;
  int half = lane >> 5;        // 0 = even neighbor, 1 = odd neighbor
  int l32 = lane & 31;         // feature block: features l32*8 .. +7
  const ushort* xpb = xp + l32 * 8;
  int s = rowptr[node], e = rowptr[node + 1];
  float a[8];
#pragma unroll
  for (int k = 0; k < 8; ++k) a[k] = 0.f;

  for (int base = s; base < e; base += 64) {
    int cnt = min(64, e - base);
    int my = (lane < cnt) ? eidx[base + lane] : 0;
    int full = cnt >> 1;       // neighbor pairs
    int it = 0;
    // 4-deep batches: 4 independent 16B loads in flight
    for (; it + 4 <= full; it += 4) {
      int sn0 = __shfl(my, 2 * it + half);
      int sn1 = __shfl(my, 2 * it + 2 + half);
      int sn2 = __shfl(my, 2 * it + 4 + half);
      int sn3 = __shfl(my, 2 * it + 6 + half);
      u16x8 v0 = *(const u16x8*)&xpb[(size_t)sn0 * 256];
      u16x8 v1 = *(const u16x8*)&xpb[(size_t)sn1 * 256];
      u16x8 v2 = *(const u16x8*)&xpb[(size_t)sn2 * 256];
      u16x8 v3 = *(const u16x8*)&xpb[(size_t)sn3 * 256];
#pragma unroll
      for (int k = 0; k < 8; ++k) {
        float t01 = b2f(v0[k]) + b2f(v1[k]);
        float t23 = b2f(v2[k]) + b2f(v3[k]);
        a[k] += t01 + t23;
      }
    }
    for (; it < full; ++it) {
      int sn = __shfl(my, 2 * it + half);
      u16x8 v = *(const u16x8*)&xpb[(size_t)sn * 256];
#pragma unroll
      for (int k = 0; k < 8; ++k) a[k] += b2f(v[k]);
    }
    if (cnt & 1) {
      int sn = __shfl(my, cnt - 1);
      if (half == 0) {
        u16x8 v = *(const u16x8*)&xpb[(size_t)sn * 256];
#pragma unroll
        for (int k = 0; k < 8; ++k) a[k] += b2f(v[k]);
      }
    }
  }
#pragma unroll
  for (int k = 0; k < 8; ++k) a[k] += __shfl_xor(a[k], 32);

  int c = e - s; if (c < 1) c = 1;
  float inv = 1.f / (float)c;
  if (half == 0) {
    u16x8 o;
#pragma unroll
    for (int k = 0; k < 8; ++k) o[k] = f2b(a[k] * inv);
    *(u16x8*)&mean[(size_t)node * 256 + l32 * 8] = o;
  }
}

// ---------------- MFMA GEMM: C = act(A1@B1^T + A2@B2^T + bias) ----------------
#define GLD16(g, l) \
  __builtin_amdgcn_global_load_lds((const __attribute__((address_space(1))) void*)(g), \
                                   (__attribute__((address_space(3))) void*)(l), 16, 0, 0)

__global__ __launch_bounds__(256, 2)
void gemm_bf16(const ushort* __restrict__ A1, const ushort* __restrict__ B1,
               const ushort* __restrict__ A2, const ushort* __restrict__ B2,
               const ushort* __restrict__ bias, ushort* __restrict__ C,
               float* __restrict__ Cf, const int* __restrict__ flag,
               int M, int N, int K1, int K2, int do_relu) {
  __shared__ __align__(16) ushort lsA[128 * 32];
  __shared__ __align__(16) ushort lsB[128 * 32];
  const int tid = threadIdx.x;
  const int lane = tid & 63;
  const int wid = tid >> 6;
  const int wr = wid >> 1, wc = wid & 1;
  const int m0 = blockIdx.x * 128;
  const int n0 = blockIdx.y * 128;
  const int l15 = lane & 15;
  const int lg = lane >> 4;
  const int fl = Cf ? *flag : 0;

  f32x4 acc[4][4];
#pragma unroll
  for (int i = 0; i < 4; ++i)
#pragma unroll
    for (int j = 0; j < 4; ++j) {
      acc[i][j][0] = 0.f; acc[i][j][1] = 0.f; acc[i][j][2] = 0.f; acc[i][j][3] = 0.f;
    }

#pragma unroll
  for (int pass = 0; pass < 2; ++pass) {
    const ushort* A = pass ? A2 : A1;
    const ushort* B = pass ? B2 : B1;
    const int K = pass ? K2 : K1;
    if (K == 0) continue;
    for (int k0 = 0; k0 < K; k0 += 32) {
#pragma unroll
      for (int it = 0; it < 2; ++it) {
        int o = tid * 16 + it * 4096;   // byte offset within 8KB tile
        int row = o >> 6;               // 64 bytes per row
        int colb = o & 63;
        const ushort* ga = A + (size_t)(m0 + row) * K + k0 + (colb >> 1);
        GLD16(ga, (char*)lsA + o);
        const ushort* gb = B + (size_t)(n0 + row) * K + k0 + (colb >> 1);
        GLD16(gb, (char*)lsB + o);
      }
      __syncthreads();
      s16x8 af[4], bfr[4];
#pragma unroll
      for (int i = 0; i < 4; ++i)
        af[i] = *(const s16x8*)&lsA[(wr * 64 + i * 16 + l15) * 32 + lg * 8];
#pragma unroll
      for (int j = 0; j < 4; ++j)
        bfr[j] = *(const s16x8*)&lsB[(wc * 64 + j * 16 + l15) * 32 + lg * 8];
#pragma unroll
      for (int i = 0; i < 4; ++i)
#pragma unroll
        for (int j = 0; j < 4; ++j)
          acc[i][j] = __builtin_amdgcn_mfma_f32_16x16x32_bf16(af[i], bfr[j], acc[i][j], 0, 0, 0);
      __syncthreads();
    }
  }

#pragma unroll
  for (int j = 0; j < 4; ++j) {
    int col = n0 + wc * 64 + j * 16 + l15;
    float bv = bias ? b2f(bias[col]) : 0.f;
#pragma unroll
    for (int i = 0; i < 4; ++i) {
      int rbase = m0 + wr * 64 + i * 16 + lg * 4;
#pragma unroll
      for (int r = 0; r < 4; ++r) {
        float v = acc[i][j][r] + bv;
        if (do_relu) v = fmaxf(v, 0.f);
        size_t idx = (size_t)(rbase + r) * N + col;
        if (Cf) {
          if (fl) Cf[idx] = v;
          else    C[idx] = f2b(v);
        } else {
          C[idx] = f2b(v);
        }
      }
    }
  }
}

// ---------------- kriging gather (reads dual-dtype h region of d_out) ----------------
__global__ void gather_out(const ushort* __restrict__ hb, const float* __restrict__ hf,
                           const int* __restrict__ map_id, void* __restrict__ dout,
                           const int* __restrict__ flag,
                           int K, int num_nodes, int total, int N) {
  int i = blockIdx.x * 256 + threadIdx.x;
  if (i >= total) return;
  int f = i & 127;
  int row = i >> 7;
  int b = row / K;
  unsigned node = (unsigned)(b * num_nodes + map_id[row]);
  bool ok = node < (unsigned)N;
  if (*flag) {
    ((float*)dout)[i] = ok ? hf[(size_t)node * 128 + f] : 0.f;
  } else {
    ((ushort*)dout)[i] = ok ? hb[(size_t)node * 128 + f] : (ushort)0;
  }
}

extern "C" void kernel_launch(void* const* d_in, const int* in_sizes, int n_in,
                              void* d_out, int out_size, void* d_ws, size_t ws_size,
                              hipStream_t stream) {
  const void* x    = d_in[0];
  const int*  ei   = (const int*)d_in[1];
  const int*  mapi = (const int*)d_in[2];
  const void* Wp1  = d_in[4];
  const void* bp1  = d_in[5];
  const void* Wl1  = d_in[6];
  const void* bl1  = d_in[7];
  const void* Wr1  = d_in[8];
  const void* Wp2  = d_in[9];
  const void* bp2  = d_in[10];
  const void* Wl2  = d_in[11];
  const void* bl2  = d_in[12];
  const void* Wr2  = d_in[13];
  const void* Wlin = d_in[14];
  const void* blin = d_in[15];

  const int NN = in_sizes[0] / 256;   // 80000
  const int E  = in_sizes[1] / 2;     // 1.28M
  const int MAPROWS = in_sizes[2];    // 40000
  const int BS = 16;
  const int NUM_NODES = NN / BS;      // 5000
  const int KMAP = MAPROWS / BS;      // 2500
  const int NBUCK = (NN + 511) >> 9;  // 157 buckets of 512 nodes
  const int* src = ei;
  const int* dst = ei + E;

  ushort* houtB = (ushort*)d_out + (size_t)MAPROWS * 128;
  float*  houtF = (float*)d_out + (size_t)MAPROWS * 128;

  int2* pairs = (int2*)((char*)d_out + (size_t)MAPROWS * 128 * 4);

  char* sc = (char*)d_out;
  auto carve_sc = [&](size_t bytes) {
    char* p = sc; sc += (bytes + 255) & ~(size_t)255; return p;
  };
  ushort* Wp1T  = (ushort*)carve_sc(256 * 256 * 2);
  ushort* Wl1T  = (ushort*)carve_sc(256 * 256 * 2);
  ushort* Wr1T  = (ushort*)carve_sc(256 * 256 * 2);
  ushort* Wp2T  = (ushort*)carve_sc(256 * 256 * 2);
  ushort* Wl2T  = (ushort*)carve_sc(128 * 256 * 2);
  ushort* Wr2T  = (ushort*)carve_sc(128 * 256 * 2);
  ushort* WlinT = (ushort*)carve_sc(128 * 128 * 2);
  ushort* bp1c  = (ushort*)carve_sc(256 * 2);
  ushort* bl1c  = (ushort*)carve_sc(256 * 2);
  ushort* bp2c  = (ushort*)carve_sc(256 * 2);
  ushort* bl2c  = (ushort*)carve_sc(128 * 2);
  ushort* blinc = (ushort*)carve_sc(128 * 2);
  int* deg    = (int*)carve_sc((size_t)NN * 4);
  int* rowptr = (int*)carve_sc(((size_t)NN + 1) * 4);
  int* pos    = (int*)carve_sc((size_t)NN * 4);
  int* eidx   = (int*)carve_sc((size_t)E * 4);
  int* bsum   = (int*)carve_sc(1024);
  int* ebsum  = (int*)carve_sc(1024);
  int* bcnt   = (int*)carve_sc(2048);
  int* bscan  = (int*)carve_sc(2048 + 4);
  int* bpos   = (int*)carve_sc(2048);

  char* w = (char*)d_ws;
  auto carve = [&](size_t bytes) {
    char* p = w; w += (bytes + 255) & ~(size_t)255; return p;
  };
  int*    flag = (int*)carve(256);
  ushort* xb   = (ushort*)carve((size_t)NN * 256 * 2);  // x_bf16 -> mean2
  ushort* bA   = (ushort*)carve((size_t)NN * 256 * 2);  // xp1 -> h1
  ushort* bB   = (ushort*)carve((size_t)NN * 256 * 2);  // mean1 -> xp2 -> h2

  // --- dtype detect + conversions ---
  detect_dtype<<<dim3(1), 256, 0, stream>>>((const ushort*)x, flag);
  convert_x<<<dim3((NN * 256 / 4 + 255) / 256), 256, 0, stream>>>(x, xb, flag, NN * 256);

  WPack wp;
  wp.d[0] = {Wp1, Wp1T, 256, 256};
  wp.d[1] = {Wl1, Wl1T, 256, 256};
  wp.d[2] = {Wr1, Wr1T, 256, 256};
  wp.d[3] = {Wp2, Wp2T, 256, 256};
  wp.d[4] = {Wl2, Wl2T, 256, 128};
  wp.d[5] = {Wr2, Wr2T, 256, 128};
  wp.d[6] = {Wlin, WlinT, 128, 128};
  transpose_convert_all<<<dim3(256, 7), 256, 0, stream>>>(wp, flag);

  BPack bp;
  bp.d[0] = {bp1, bp1c, 256, 1};
  bp.d[1] = {bl1, bl1c, 256, 1};
  bp.d[2] = {bp2, bp2c, 256, 1};
  bp.d[3] = {bl2, bl2c, 128, 1};
  bp.d[4] = {blin, blinc, 128, 1};
  convert_vec_all<<<dim3(1, 5), 256, 0, stream>>>(bp, flag);

  // --- CSR build (two-level counting sort) ---
  hipMemsetAsync(deg, 0, (size_t)NN * 4, stream);
  hipMemsetAsync(bcnt, 0, 2048, stream);
  hist_bucket_kernel<<<dim3((E + 2047) / 2048), 256, 0, stream>>>(dst, deg, bcnt, E, NN, NBUCK);
  scan_buckets<<<dim3(1), 256, 0, stream>>>(bcnt, bscan, bpos, NBUCK);
  int SB = (NN + 1023) / 1024;
  scan_phaseA<<<dim3(SB), 256, 0, stream>>>(deg, bsum, NN);
  scan_phaseB<<<dim3(1), 256, 0, stream>>>(bsum, ebsum, rowptr, SB, NN);
  scan_phaseC<<<dim3(SB), 256, 0, stream>>>(deg, ebsum, rowptr, pos, NN);
  bin_scatter<<<dim3((E + 4095) / 4096), 256, 0, stream>>>(src, dst, bpos, pairs, E, NN, NBUCK);
  final_scatter<<<dim3(NBUCK * FS_SPLIT), 256, 0, stream>>>(pairs, bscan, pos, eidx, E);

  dim3 blk(256);
  dim3 g256(NN / 128, 2);   // N=256
  dim3 g128(NN / 128, 1);   // N=128
  dim3 gagg((NN + 3) / 4);

  // --- layer 1 ---
  gemm_bf16<<<g256, blk, 0, stream>>>(xb, Wp1T, nullptr, nullptr, bp1c, bA,
                                      nullptr, nullptr, NN, 256, 256, 0, 1);        // xp1
  agg_mean_v4<<<gagg, blk, 0, stream>>>(bA, rowptr, eidx, bB, NN);                  // mean1
  gemm_bf16<<<g256, blk, 0, stream>>>(bB, Wl1T, xb, Wr1T, bl1c, bA,
                                      nullptr, nullptr, NN, 256, 256, 256, 1);      // h1

  // --- layer 2 ---
  gemm_bf16<<<g256, blk, 0, stream>>>(bA, Wp2T, nullptr, nullptr, bp2c, bB,
                                      nullptr, nullptr, NN, 256, 256, 0, 1);        // xp2
  agg_mean_v4<<<gagg, blk, 0, stream>>>(bB, rowptr, eidx, xb, NN);                  // mean2
  gemm_bf16<<<g128, blk, 0, stream>>>(xb, Wl2T, bA, Wr2T, bl2c, bB,
                                      nullptr, nullptr, NN, 128, 256, 256, 1);      // h2

  // --- final linear: write dual-dtype h straight into d_out h region ---
  gemm_bf16<<<g128, blk, 0, stream>>>(bB, WlinT, nullptr, nullptr, blinc, houtB,
                                      houtF, flag, NN, 128, 128, 0, 0);

  // --- kriging gather -> d_out local_feat region (overwrites scratch, last use) ---
  int total = MAPROWS * 128;
  gather_out<<<dim3((total + 255) / 256), 256, 0, stream>>>(houtB, houtF, mapi, d_out,
                                                            flag, KMAP, NUM_NODES, total, NN);
}